// Round 1
// baseline (1351.301 us; speedup 1.0000x reference)
//
#include <hip/hip_runtime.h>
#include <cstddef>
#include <cstdint>

#define IN_DIM 512
#define R_DIM 128
#define F_DIM 64
#define H_NUM 4
#define OUT_DIM 64
#define HF 256  // H_NUM * F_DIM

// ---------------------------------------------------------------- zero fill
__global__ __launch_bounds__(256) void zero_f32(float* __restrict__ p, size_t n) {
    size_t i = (size_t)blockIdx.x * blockDim.x + threadIdx.x;
    size_t stride = (size_t)gridDim.x * blockDim.x;
    for (; i < n; i += stride) p[i] = 0.0f;
}

// ------------------------------------------------- fold W_seq @ W_lin (heads)
// Wc[h][f][i] = sum_r Wseq[h][f][r] * Wlin[h][r][i]
__global__ __launch_bounds__(256) void wcomb1_kernel(const float* __restrict__ Wlin,
                                                     const float* __restrict__ Wseq,
                                                     float* __restrict__ Wc) {
    int idx = blockIdx.x * 256 + threadIdx.x;
    if (idx >= H_NUM * F_DIM * IN_DIM) return;
    int i  = idx & (IN_DIM - 1);
    int hf = idx >> 9;          // h*64 + f
    int h  = hf >> 6;
    const float* ws = Wseq + (size_t)hf * R_DIM;
    const float* wl = Wlin + (size_t)h * R_DIM * IN_DIM + i;
    float acc = 0.0f;
#pragma unroll 8
    for (int r = 0; r < R_DIM; ++r) acc += ws[r] * wl[(size_t)r * IN_DIM];
    Wc[idx] = acc;
}

// ---------------------------------------------- fold W_seq_c @ W_lin_c (clf)
// Wc2[o][j] = sum_r Wseq_c[o][r] * Wlin_c[r][j]
__global__ __launch_bounds__(256) void wcomb2_kernel(const float* __restrict__ Wlin,
                                                     const float* __restrict__ Wseq,
                                                     float* __restrict__ Wc) {
    int idx = blockIdx.x * 256 + threadIdx.x;
    if (idx >= OUT_DIM * HF) return;
    int j = idx & (HF - 1);
    int o = idx >> 8;
    const float* ws = Wseq + (size_t)o * R_DIM;
    const float* wl = Wlin + j;
    float acc = 0.0f;
#pragma unroll 8
    for (int r = 0; r < R_DIM; ++r) acc += ws[r] * wl[(size_t)r * HF];
    Wc[idx] = acc;
}

// ------------------------------------------------------- fp32 tiled GEMM T-N
// C[m][n] = sum_k A[m*K + k] * W[n*K + k]   (A row-major, W row-major [N][K])
// 64x64 tile, 256 threads, 4x4 microtile, K-step 16.
__global__ __launch_bounds__(256) void gemm_tn(const float* __restrict__ A,
                                               const float* __restrict__ W,
                                               float* __restrict__ C,
                                               int M, int N, int K) {
    __shared__ __align__(16) float As[16][68];
    __shared__ __align__(16) float Ws[16][68];
    const int tid = threadIdx.x;
    const int m0 = blockIdx.x * 64;
    const int n0 = blockIdx.y * 64;
    const int lr = tid >> 4;   // 0..15
    const int lc = tid & 15;   // 0..15
    const int lrow = tid >> 2; // 0..63  row loaded by this thread
    const int lk   = (tid & 3) * 4;  // k-offset of this thread's float4
    float acc[4][4] = {};

    const int arow = m0 + lrow;
    const int wrow = n0 + lrow;   // always < N (N multiple of 64)

    for (int k0 = 0; k0 < K; k0 += 16) {
        float4 av = make_float4(0.f, 0.f, 0.f, 0.f);
        if (arow < M) av = *(const float4*)(A + (size_t)arow * K + k0 + lk);
        float4 wv = *(const float4*)(W + (size_t)wrow * K + k0 + lk);
        As[lk + 0][lrow] = av.x;
        As[lk + 1][lrow] = av.y;
        As[lk + 2][lrow] = av.z;
        As[lk + 3][lrow] = av.w;
        Ws[lk + 0][lrow] = wv.x;
        Ws[lk + 1][lrow] = wv.y;
        Ws[lk + 2][lrow] = wv.z;
        Ws[lk + 3][lrow] = wv.w;
        __syncthreads();
#pragma unroll
        for (int kk = 0; kk < 16; ++kk) {
            const float4 a = *(const float4*)&As[kk][lr * 4];
            const float4 b = *(const float4*)&Ws[kk][lc * 4];
            acc[0][0] += a.x * b.x; acc[0][1] += a.x * b.y; acc[0][2] += a.x * b.z; acc[0][3] += a.x * b.w;
            acc[1][0] += a.y * b.x; acc[1][1] += a.y * b.y; acc[1][2] += a.y * b.z; acc[1][3] += a.y * b.w;
            acc[2][0] += a.z * b.x; acc[2][1] += a.z * b.y; acc[2][2] += a.z * b.z; acc[2][3] += a.z * b.w;
            acc[3][0] += a.w * b.x; acc[3][1] += a.w * b.y; acc[3][2] += a.w * b.z; acc[3][3] += a.w * b.w;
        }
        __syncthreads();
    }
#pragma unroll
    for (int i = 0; i < 4; ++i) {
        int m = m0 + lr * 4 + i;
        if (m < M) {
            float4 v = make_float4(acc[i][0], acc[i][1], acc[i][2], acc[i][3]);
            *(float4*)(C + (size_t)m * N + n0 + lc * 4) = v;
        }
    }
}

// ------------------------------------------- f1/f2 dots, heads layer (wave/nh)
__global__ __launch_bounds__(256) void fvec_h_kernel(const float* __restrict__ S,
                                                     const float* __restrict__ a1,
                                                     const float* __restrict__ b1,
                                                     const float* __restrict__ a2,
                                                     const float* __restrict__ b2,
                                                     float* __restrict__ f1,
                                                     float* __restrict__ f2,
                                                     int NH) {
    int w = (int)((blockIdx.x * blockDim.x + threadIdx.x) >> 6);
    int lane = threadIdx.x & 63;
    if (w >= NH) return;
    int n = w >> 2;       // w / H
    int h = w & 3;        // w % H
    float s = S[(size_t)n * HF + h * 64 + lane];
    float p1 = s * a1[h * 64 + lane];
    float p2 = s * a2[h * 64 + lane];
#pragma unroll
    for (int off = 32; off > 0; off >>= 1) {
        p1 += __shfl_down(p1, off, 64);
        p2 += __shfl_down(p2, off, 64);
    }
    if (lane == 0) {
        f1[w] = p1 + b1[h];
        f2[w] = p2 + b2[h];
    }
}

// ------------------------------------------- f1/f2 dots, classifier (wave/n)
__global__ __launch_bounds__(256) void fvec_c_kernel(const float* __restrict__ S,
                                                     const float* __restrict__ a1,
                                                     const float* __restrict__ b1,
                                                     const float* __restrict__ a2,
                                                     const float* __restrict__ b2,
                                                     float* __restrict__ f1,
                                                     float* __restrict__ f2,
                                                     int N) {
    int w = (int)((blockIdx.x * blockDim.x + threadIdx.x) >> 6);
    int lane = threadIdx.x & 63;
    if (w >= N) return;
    float s = S[(size_t)w * OUT_DIM + lane];
    float p1 = s * a1[lane];
    float p2 = s * a2[lane];
#pragma unroll
    for (int off = 32; off > 0; off >>= 1) {
        p1 += __shfl_down(p1, off, 64);
        p2 += __shfl_down(p2, off, 64);
    }
    if (lane == 0) {
        f1[w] = p1 + b1[0];
        f2[w] = p2 + b2[0];
    }
}

// --------------------------------------------------- edge scatter, heads layer
// one wave per edge; loops over 4 heads; 64 lanes cover F=64
__global__ __launch_bounds__(256) void edge1_kernel(const int* __restrict__ src,
                                                    const int* __restrict__ dst,
                                                    const float* __restrict__ f1,
                                                    const float* __restrict__ f2,
                                                    const float* __restrict__ S1,
                                                    float* __restrict__ agg,
                                                    float* __restrict__ den,
                                                    int E) {
    int w = (int)((blockIdx.x * blockDim.x + threadIdx.x) >> 6);
    int lane = threadIdx.x & 63;
    if (w >= E) return;
    int s = src[w];
    int d = dst[w];
    const float* srow = S1 + (size_t)d * HF;
    float* arow = agg + (size_t)s * HF;
#pragma unroll
    for (int h = 0; h < H_NUM; ++h) {
        float logit = f1[(size_t)s * H_NUM + h] + f2[(size_t)d * H_NUM + h];
        float l = logit > 0.0f ? logit : 0.2f * logit;
        float c = expf(l);
        atomicAdd(&arow[h * 64 + lane], c * srow[h * 64 + lane]);
        if (lane == 0) atomicAdd(&den[(size_t)s * H_NUM + h], c);
    }
}

// --------------------------------------------------- edge scatter, classifier
__global__ __launch_bounds__(256) void edge2_kernel(const int* __restrict__ src,
                                                    const int* __restrict__ dst,
                                                    const float* __restrict__ f1,
                                                    const float* __restrict__ f2,
                                                    const float* __restrict__ S2,
                                                    float* __restrict__ agg,
                                                    float* __restrict__ den,
                                                    int E) {
    int w = (int)((blockIdx.x * blockDim.x + threadIdx.x) >> 6);
    int lane = threadIdx.x & 63;
    if (w >= E) return;
    int s = src[w];
    int d = dst[w];
    float logit = f1[s] + f2[d];
    float l = logit > 0.0f ? logit : 0.2f * logit;
    float c = expf(l);
    atomicAdd(&agg[(size_t)s * OUT_DIM + lane], c * S2[(size_t)d * OUT_DIM + lane]);
    if (lane == 0) atomicAdd(&den[s], c);
}

// ------------------------------------------------- finalize heads (ELU, in place)
__global__ __launch_bounds__(256) void finalize1_kernel(float* __restrict__ agg,
                                                        const float* __restrict__ den,
                                                        const float* __restrict__ bias,
                                                        int N) {
    size_t i = (size_t)blockIdx.x * blockDim.x + threadIdx.x;
    if (i >= (size_t)N * HF) return;
    int n = (int)(i >> 8);
    int c = (int)(i & (HF - 1));
    int h = c >> 6;
    float v = agg[i] / den[(size_t)n * H_NUM + h] + bias[c];
    agg[i] = v > 0.0f ? v : expm1f(v);
}

// ------------------------------------------------- finalize classifier (no ELU)
__global__ __launch_bounds__(256) void finalize2_kernel(float* __restrict__ out,
                                                        const float* __restrict__ den,
                                                        const float* __restrict__ bias,
                                                        int N) {
    size_t i = (size_t)blockIdx.x * blockDim.x + threadIdx.x;
    if (i >= (size_t)N * OUT_DIM) return;
    int n = (int)(i >> 6);
    int j = (int)(i & 63);
    out[i] = out[i] / den[n] + bias[j];
}

// ===========================================================================
extern "C" void kernel_launch(void* const* d_in, const int* in_sizes, int n_in,
                              void* d_out, int out_size, void* d_ws, size_t ws_size,
                              hipStream_t stream) {
    const float* x      = (const float*)d_in[0];
    const int*   edges  = (const int*)d_in[1];
    const float* Wlin_h = (const float*)d_in[2];
    const float* Wseq_h = (const float*)d_in[3];
    const float* a1_h   = (const float*)d_in[4];
    const float* b1_h   = (const float*)d_in[5];
    const float* a2_h   = (const float*)d_in[6];
    const float* b2_h   = (const float*)d_in[7];
    const float* bias_h = (const float*)d_in[8];
    const float* Wlin_c = (const float*)d_in[9];
    const float* Wseq_c = (const float*)d_in[10];
    const float* a1_c   = (const float*)d_in[11];
    const float* b1_c   = (const float*)d_in[12];
    const float* a2_c   = (const float*)d_in[13];
    const float* b2_c   = (const float*)d_in[14];
    const float* bias_c = (const float*)d_in[15];

    const int N = in_sizes[0] / IN_DIM;
    const int E = in_sizes[1] / 2;
    const int* src = edges;
    const int* dst = edges + E;

    float* ws = (float*)d_ws;
    size_t off = 0;
    float* Wc1  = ws + off; off += (size_t)H_NUM * F_DIM * IN_DIM;  // 131072
    float* Wc2  = ws + off; off += (size_t)OUT_DIM * HF;            // 16384
    float* S1   = ws + off; off += (size_t)N * HF;
    float* S2   = ws + off; off += (size_t)N * OUT_DIM;
    // zero-region begins here (contiguous): AGG1, DEN1, DEN2
    float* AGG1 = ws + off; off += (size_t)N * HF;
    float* DEN1 = ws + off; off += (size_t)N * H_NUM;
    float* DEN2 = ws + off; off += (size_t)N;
    size_t zero_span = (size_t)N * HF + (size_t)N * H_NUM + (size_t)N;
    // non-zeroed scratch
    float* F1   = ws + off; off += (size_t)N * H_NUM;
    float* F2   = ws + off; off += (size_t)N * H_NUM;
    float* F1c  = ws + off; off += (size_t)N;
    float* F2c  = ws + off; off += (size_t)N;

    float* out = (float*)d_out;

    // ---- zero accumulators + output (output doubles as classifier agg buffer)
    hipLaunchKernelGGL(zero_f32, dim3(2048), dim3(256), 0, stream, AGG1, zero_span);
    hipLaunchKernelGGL(zero_f32, dim3(1024), dim3(256), 0, stream, out, (size_t)N * OUT_DIM);

    // ---- fold weights
    hipLaunchKernelGGL(wcomb1_kernel, dim3((H_NUM * F_DIM * IN_DIM + 255) / 256), dim3(256),
                       0, stream, Wlin_h, Wseq_h, Wc1);
    hipLaunchKernelGGL(wcomb2_kernel, dim3((OUT_DIM * HF + 255) / 256), dim3(256),
                       0, stream, Wlin_c, Wseq_c, Wc2);

    // ---- layer 1: S1 = x @ Wc1^T   [N,512] x [256,512] -> [N,256]
    hipLaunchKernelGGL(gemm_tn, dim3((N + 63) / 64, HF / 64), dim3(256), 0, stream,
                       x, Wc1, S1, N, HF, IN_DIM);

    // ---- f1/f2 per (node, head)
    hipLaunchKernelGGL(fvec_h_kernel, dim3((N * H_NUM + 3) / 4), dim3(256), 0, stream,
                       S1, a1_h, b1_h, a2_h, b2_h, F1, F2, N * H_NUM);

    // ---- edge scatter layer 1
    hipLaunchKernelGGL(edge1_kernel, dim3((E + 3) / 4), dim3(256), 0, stream,
                       src, dst, F1, F2, S1, AGG1, DEN1, E);

    // ---- finalize layer 1 (in place -> hcat)
    hipLaunchKernelGGL(finalize1_kernel, dim3((int)(((size_t)N * HF + 255) / 256)), dim3(256),
                       0, stream, AGG1, DEN1, bias_h, N);

    // ---- classifier: S2 = hcat @ Wc2^T   [N,256] x [64,256] -> [N,64]
    hipLaunchKernelGGL(gemm_tn, dim3((N + 63) / 64, OUT_DIM / 64), dim3(256), 0, stream,
                       AGG1, Wc2, S2, N, OUT_DIM, HF);

    // ---- f1/f2 classifier
    hipLaunchKernelGGL(fvec_c_kernel, dim3((N + 3) / 4), dim3(256), 0, stream,
                       S2, a1_c, b1_c, a2_c, b2_c, F1c, F2c, N);

    // ---- edge scatter classifier (accumulates into d_out)
    hipLaunchKernelGGL(edge2_kernel, dim3((E + 3) / 4), dim3(256), 0, stream,
                       src, dst, F1c, F2c, S2, out, DEN2, E);

    // ---- finalize classifier
    hipLaunchKernelGGL(finalize2_kernel, dim3((int)(((size_t)N * OUT_DIM + 255) / 256)), dim3(256),
                       0, stream, out, DEN2, bias_c, N);
}

// Round 2
// 777.496 us; speedup vs baseline: 1.7380x; 1.7380x over previous
//
#include <hip/hip_runtime.h>
#include <cstddef>
#include <cstdint>

#define IN_DIM 512
#define R_DIM 128
#define F_DIM 64
#define H_NUM 4
#define OUT_DIM 64
#define HF 256  // H_NUM * F_DIM

// ---------------------------------------------------------------- zero ints
__global__ __launch_bounds__(256) void zero_i32(int* __restrict__ p, int n) {
    int i = blockIdx.x * 256 + threadIdx.x;
    if (i < n) p[i] = 0;
}

// ------------------------------------------------- fold W_seq @ W_lin (heads)
__global__ __launch_bounds__(256) void wcomb1_kernel(const float* __restrict__ Wlin,
                                                     const float* __restrict__ Wseq,
                                                     float* __restrict__ Wc) {
    int idx = blockIdx.x * 256 + threadIdx.x;
    if (idx >= H_NUM * F_DIM * IN_DIM) return;
    int i  = idx & (IN_DIM - 1);
    int hf = idx >> 9;          // h*64 + f
    int h  = hf >> 6;
    const float* ws = Wseq + (size_t)hf * R_DIM;
    const float* wl = Wlin + (size_t)h * R_DIM * IN_DIM + i;
    float acc = 0.0f;
#pragma unroll 8
    for (int r = 0; r < R_DIM; ++r) acc += ws[r] * wl[(size_t)r * IN_DIM];
    Wc[idx] = acc;
}

// ---------------------------------------------- fold W_seq_c @ W_lin_c (clf)
__global__ __launch_bounds__(256) void wcomb2_kernel(const float* __restrict__ Wlin,
                                                     const float* __restrict__ Wseq,
                                                     float* __restrict__ Wc) {
    int idx = blockIdx.x * 256 + threadIdx.x;
    if (idx >= OUT_DIM * HF) return;
    int j = idx & (HF - 1);
    int o = idx >> 8;
    const float* ws = Wseq + (size_t)o * R_DIM;
    const float* wl = Wlin + j;
    float acc = 0.0f;
#pragma unroll 8
    for (int r = 0; r < R_DIM; ++r) acc += ws[r] * wl[(size_t)r * HF];
    Wc[idx] = acc;
}

// ------------------------------------------------------- fp32 tiled GEMM T-N
__global__ __launch_bounds__(256) void gemm_tn(const float* __restrict__ A,
                                               const float* __restrict__ W,
                                               float* __restrict__ C,
                                               int M, int N, int K) {
    __shared__ __align__(16) float As[16][68];
    __shared__ __align__(16) float Ws[16][68];
    const int tid = threadIdx.x;
    const int m0 = blockIdx.x * 64;
    const int n0 = blockIdx.y * 64;
    const int lr = tid >> 4;
    const int lc = tid & 15;
    const int lrow = tid >> 2;
    const int lk   = (tid & 3) * 4;
    float acc[4][4] = {};

    const int arow = m0 + lrow;
    const int wrow = n0 + lrow;

    for (int k0 = 0; k0 < K; k0 += 16) {
        float4 av = make_float4(0.f, 0.f, 0.f, 0.f);
        if (arow < M) av = *(const float4*)(A + (size_t)arow * K + k0 + lk);
        float4 wv = *(const float4*)(W + (size_t)wrow * K + k0 + lk);
        As[lk + 0][lrow] = av.x;
        As[lk + 1][lrow] = av.y;
        As[lk + 2][lrow] = av.z;
        As[lk + 3][lrow] = av.w;
        Ws[lk + 0][lrow] = wv.x;
        Ws[lk + 1][lrow] = wv.y;
        Ws[lk + 2][lrow] = wv.z;
        Ws[lk + 3][lrow] = wv.w;
        __syncthreads();
#pragma unroll
        for (int kk = 0; kk < 16; ++kk) {
            const float4 a = *(const float4*)&As[kk][lr * 4];
            const float4 b = *(const float4*)&Ws[kk][lc * 4];
            acc[0][0] += a.x * b.x; acc[0][1] += a.x * b.y; acc[0][2] += a.x * b.z; acc[0][3] += a.x * b.w;
            acc[1][0] += a.y * b.x; acc[1][1] += a.y * b.y; acc[1][2] += a.y * b.z; acc[1][3] += a.y * b.w;
            acc[2][0] += a.z * b.x; acc[2][1] += a.z * b.y; acc[2][2] += a.z * b.z; acc[2][3] += a.z * b.w;
            acc[3][0] += a.w * b.x; acc[3][1] += a.w * b.y; acc[3][2] += a.w * b.z; acc[3][3] += a.w * b.w;
        }
        __syncthreads();
    }
#pragma unroll
    for (int i = 0; i < 4; ++i) {
        int m = m0 + lr * 4 + i;
        if (m < M) {
            float4 v = make_float4(acc[i][0], acc[i][1], acc[i][2], acc[i][3]);
            *(float4*)(C + (size_t)m * N + n0 + lc * 4) = v;
        }
    }
}

// ------------------------------------------- f1/f2 dots, heads layer (wave/nh)
__global__ __launch_bounds__(256) void fvec_h_kernel(const float* __restrict__ S,
                                                     const float* __restrict__ a1,
                                                     const float* __restrict__ b1,
                                                     const float* __restrict__ a2,
                                                     const float* __restrict__ b2,
                                                     float* __restrict__ f1,
                                                     float* __restrict__ f2,
                                                     int NH) {
    int w = (int)((blockIdx.x * blockDim.x + threadIdx.x) >> 6);
    int lane = threadIdx.x & 63;
    if (w >= NH) return;
    int n = w >> 2;
    int h = w & 3;
    float s = S[(size_t)n * HF + h * 64 + lane];
    float p1 = s * a1[h * 64 + lane];
    float p2 = s * a2[h * 64 + lane];
#pragma unroll
    for (int off = 32; off > 0; off >>= 1) {
        p1 += __shfl_down(p1, off, 64);
        p2 += __shfl_down(p2, off, 64);
    }
    if (lane == 0) {
        f1[w] = p1 + b1[h];
        f2[w] = p2 + b2[h];
    }
}

// ------------------------------------------- f1/f2 dots, classifier (wave/n)
__global__ __launch_bounds__(256) void fvec_c_kernel(const float* __restrict__ S,
                                                     const float* __restrict__ a1,
                                                     const float* __restrict__ b1,
                                                     const float* __restrict__ a2,
                                                     const float* __restrict__ b2,
                                                     float* __restrict__ f1,
                                                     float* __restrict__ f2,
                                                     int N) {
    int w = (int)((blockIdx.x * blockDim.x + threadIdx.x) >> 6);
    int lane = threadIdx.x & 63;
    if (w >= N) return;
    float s = S[(size_t)w * OUT_DIM + lane];
    float p1 = s * a1[lane];
    float p2 = s * a2[lane];
#pragma unroll
    for (int off = 32; off > 0; off >>= 1) {
        p1 += __shfl_down(p1, off, 64);
        p2 += __shfl_down(p2, off, 64);
    }
    if (lane == 0) {
        f1[w] = p1 + b1[0];
        f2[w] = p2 + b2[0];
    }
}

// ------------------------------------------------------------ CSR: histogram
__global__ __launch_bounds__(256) void hist_kernel(const int* __restrict__ src,
                                                   int* __restrict__ counts, int E) {
    int e = blockIdx.x * 256 + threadIdx.x;
    if (e < E) atomicAdd(&counts[src[e]], 1);
}

// -------------------------------------------- CSR: single-block chunked scan
__global__ __launch_bounds__(1024) void scan_kernel(const int* __restrict__ counts,
                                                    int* __restrict__ starts,
                                                    int* __restrict__ cursor, int N) {
    __shared__ int buf[1024];
    __shared__ int carry_s;
    int tid = threadIdx.x;
    if (tid == 0) carry_s = 0;
    __syncthreads();
    for (int base = 0; base < N; base += 1024) {
        int v = (base + tid < N) ? counts[base + tid] : 0;
        buf[tid] = v;
        __syncthreads();
#pragma unroll
        for (int off = 1; off < 1024; off <<= 1) {
            int t = (tid >= off) ? buf[tid - off] : 0;
            __syncthreads();
            buf[tid] += t;
            __syncthreads();
        }
        int carry = carry_s;
        int excl = carry + buf[tid] - v;
        if (base + tid < N) {
            starts[base + tid] = excl;
            cursor[base + tid] = excl;
        }
        __syncthreads();
        if (tid == 0) carry_s = carry + buf[1023];
        __syncthreads();
    }
    if (tid == 0) starts[N] = carry_s;
}

// ----------------------------------------------------- CSR: position scatter
__global__ __launch_bounds__(256) void scatter_kernel(const int* __restrict__ src,
                                                      int* __restrict__ cursor,
                                                      int* __restrict__ eid, int E) {
    int e = blockIdx.x * 256 + threadIdx.x;
    if (e >= E) return;
    int p = atomicAdd(&cursor[src[e]], 1);
    eid[p] = e;
}

// --------------------------------------------- per-edge coefs, heads (4/edge)
__global__ __launch_bounds__(256) void coef1_kernel(const int* __restrict__ src,
                                                    const int* __restrict__ dst,
                                                    const float* __restrict__ f1,
                                                    const float* __restrict__ f2,
                                                    float4* __restrict__ coef, int E) {
    int e = blockIdx.x * 256 + threadIdx.x;
    if (e >= E) return;
    int s = src[e], d = dst[e];
    float4 l1 = *(const float4*)(f1 + (size_t)s * 4);
    float4 l2 = *(const float4*)(f2 + (size_t)d * 4);
    float lx = l1.x + l2.x, ly = l1.y + l2.y, lz = l1.z + l2.z, lw = l1.w + l2.w;
    lx = lx > 0.f ? lx : 0.2f * lx;
    ly = ly > 0.f ? ly : 0.2f * ly;
    lz = lz > 0.f ? lz : 0.2f * lz;
    lw = lw > 0.f ? lw : 0.2f * lw;
    coef[e] = make_float4(expf(lx), expf(ly), expf(lz), expf(lw));
}

// ------------------------------------------------ per-edge coef, classifier
__global__ __launch_bounds__(256) void coef2_kernel(const int* __restrict__ src,
                                                    const int* __restrict__ dst,
                                                    const float* __restrict__ f1,
                                                    const float* __restrict__ f2,
                                                    float* __restrict__ coef, int E) {
    int e = blockIdx.x * 256 + threadIdx.x;
    if (e >= E) return;
    float l = f1[src[e]] + f2[dst[e]];
    l = l > 0.f ? l : 0.2f * l;
    coef[e] = expf(l);
}

// ----------------------- gather + normalize + bias + ELU, heads (wave/node)
__global__ __launch_bounds__(256) void gather1_kernel(const int* __restrict__ starts,
                                                      const int* __restrict__ eid,
                                                      const int* __restrict__ dst,
                                                      const float4* __restrict__ coef,
                                                      const float* __restrict__ S1,
                                                      const float* __restrict__ bias,
                                                      float* __restrict__ hcat, int N) {
    int n = (int)((blockIdx.x * blockDim.x + threadIdx.x) >> 6);
    int lane = threadIdx.x & 63;
    if (n >= N) return;
    int beg = starts[n], end = starts[n + 1];
    float a0 = 0.f, a1 = 0.f, a2 = 0.f, a3 = 0.f;
    float d0 = 0.f, d1 = 0.f, d2 = 0.f, d3 = 0.f;
    for (int i = beg; i < end; ++i) {
        int e = eid[i];
        int d = dst[e];
        float4 c = coef[e];
        const float* row = S1 + (size_t)d * HF;
        a0 += c.x * row[lane];
        a1 += c.y * row[64 + lane];
        a2 += c.z * row[128 + lane];
        a3 += c.w * row[192 + lane];
        d0 += c.x; d1 += c.y; d2 += c.z; d3 += c.w;
    }
    float* orow = hcat + (size_t)n * HF;
    float v0 = a0 / d0 + bias[lane];
    float v1 = a1 / d1 + bias[64 + lane];
    float v2 = a2 / d2 + bias[128 + lane];
    float v3 = a3 / d3 + bias[192 + lane];
    orow[lane]       = v0 > 0.f ? v0 : expm1f(v0);
    orow[64 + lane]  = v1 > 0.f ? v1 : expm1f(v1);
    orow[128 + lane] = v2 > 0.f ? v2 : expm1f(v2);
    orow[192 + lane] = v3 > 0.f ? v3 : expm1f(v3);
}

// --------------------------- gather + normalize + bias, classifier (wave/node)
__global__ __launch_bounds__(256) void gather2_kernel(const int* __restrict__ starts,
                                                      const int* __restrict__ eid,
                                                      const int* __restrict__ dst,
                                                      const float* __restrict__ coef,
                                                      const float* __restrict__ S2,
                                                      const float* __restrict__ bias,
                                                      float* __restrict__ out, int N) {
    int n = (int)((blockIdx.x * blockDim.x + threadIdx.x) >> 6);
    int lane = threadIdx.x & 63;
    if (n >= N) return;
    int beg = starts[n], end = starts[n + 1];
    float acc = 0.f, den = 0.f;
    for (int i = beg; i < end; ++i) {
        int e = eid[i];
        int d = dst[e];
        float c = coef[e];
        acc += c * S2[(size_t)d * OUT_DIM + lane];
        den += c;
    }
    out[(size_t)n * OUT_DIM + lane] = acc / den + bias[lane];
}

// ===========================================================================
extern "C" void kernel_launch(void* const* d_in, const int* in_sizes, int n_in,
                              void* d_out, int out_size, void* d_ws, size_t ws_size,
                              hipStream_t stream) {
    const float* x      = (const float*)d_in[0];
    const int*   edges  = (const int*)d_in[1];
    const float* Wlin_h = (const float*)d_in[2];
    const float* Wseq_h = (const float*)d_in[3];
    const float* a1_h   = (const float*)d_in[4];
    const float* b1_h   = (const float*)d_in[5];
    const float* a2_h   = (const float*)d_in[6];
    const float* b2_h   = (const float*)d_in[7];
    const float* bias_h = (const float*)d_in[8];
    const float* Wlin_c = (const float*)d_in[9];
    const float* Wseq_c = (const float*)d_in[10];
    const float* a1_c   = (const float*)d_in[11];
    const float* b1_c   = (const float*)d_in[12];
    const float* a2_c   = (const float*)d_in[13];
    const float* b2_c   = (const float*)d_in[14];
    const float* bias_c = (const float*)d_in[15];

    const int N = in_sizes[0] / IN_DIM;
    const int E = in_sizes[1] / 2;
    const int* src = edges;
    const int* dst = edges + E;

    float* ws = (float*)d_ws;
    size_t off = 0;
    float* Wc1   = ws + off; off += (size_t)H_NUM * F_DIM * IN_DIM;  // 131072
    float* Wc2   = ws + off; off += (size_t)OUT_DIM * HF;            // 16384
    float* S1    = ws + off; off += (size_t)N * HF;   // S2 aliases front of S1
    float* S2    = S1;
    float* HCAT  = ws + off; off += (size_t)N * HF;
    float* COEF1 = ws + off; off += (size_t)E * 4;    // COEF2 aliases front
    float* COEF2 = COEF1;
    float* F1    = ws + off; off += (size_t)N * H_NUM;
    float* F2    = ws + off; off += (size_t)N * H_NUM;
    float* F1c   = ws + off; off += (size_t)N;
    float* F2c   = ws + off; off += (size_t)N;
    int* COUNTS  = (int*)(ws + off); off += (size_t)N;
    int* STARTS  = (int*)(ws + off); off += (size_t)N + 1;
    int* CURSOR  = (int*)(ws + off); off += (size_t)N;
    int* EID     = (int*)(ws + off); off += (size_t)E;

    float* out = (float*)d_out;

    const int eg = (E + 255) / 256;   // edge-parallel grid
    const int ng = (N + 255) / 256;

    // ---- CSR build (independent of GEMM; shared by both layers)
    hipLaunchKernelGGL(zero_i32, dim3(ng), dim3(256), 0, stream, COUNTS, N);
    hipLaunchKernelGGL(hist_kernel, dim3(eg), dim3(256), 0, stream, src, COUNTS, E);
    hipLaunchKernelGGL(scan_kernel, dim3(1), dim3(1024), 0, stream, COUNTS, STARTS, CURSOR, N);
    hipLaunchKernelGGL(scatter_kernel, dim3(eg), dim3(256), 0, stream, src, CURSOR, EID, E);

    // ---- fold weights
    hipLaunchKernelGGL(wcomb1_kernel, dim3((H_NUM * F_DIM * IN_DIM + 255) / 256), dim3(256),
                       0, stream, Wlin_h, Wseq_h, Wc1);
    hipLaunchKernelGGL(wcomb2_kernel, dim3((OUT_DIM * HF + 255) / 256), dim3(256),
                       0, stream, Wlin_c, Wseq_c, Wc2);

    // ---- layer 1: S1 = x @ Wc1^T   [N,512] x [256,512] -> [N,256]
    hipLaunchKernelGGL(gemm_tn, dim3((N + 63) / 64, HF / 64), dim3(256), 0, stream,
                       x, Wc1, S1, N, HF, IN_DIM);

    // ---- f1/f2 per (node, head), then per-edge coefs
    hipLaunchKernelGGL(fvec_h_kernel, dim3((N * H_NUM + 3) / 4), dim3(256), 0, stream,
                       S1, a1_h, b1_h, a2_h, b2_h, F1, F2, N * H_NUM);
    hipLaunchKernelGGL(coef1_kernel, dim3(eg), dim3(256), 0, stream,
                       src, dst, F1, F2, (float4*)COEF1, E);

    // ---- gather layer 1 (fused normalize + bias + ELU) -> HCAT
    hipLaunchKernelGGL(gather1_kernel, dim3((N + 3) / 4), dim3(256), 0, stream,
                       STARTS, EID, dst, (const float4*)COEF1, S1, bias_h, HCAT, N);

    // ---- classifier: S2 = hcat @ Wc2^T   [N,256] x [64,256] -> [N,64]
    hipLaunchKernelGGL(gemm_tn, dim3((N + 63) / 64, OUT_DIM / 64), dim3(256), 0, stream,
                       HCAT, Wc2, S2, N, OUT_DIM, HF);

    // ---- f1/f2 classifier, per-edge coefs
    hipLaunchKernelGGL(fvec_c_kernel, dim3((N + 3) / 4), dim3(256), 0, stream,
                       S2, a1_c, b1_c, a2_c, b2_c, F1c, F2c, N);
    hipLaunchKernelGGL(coef2_kernel, dim3(eg), dim3(256), 0, stream,
                       src, dst, F1c, F2c, COEF2, E);

    // ---- gather classifier (fused normalize + bias) -> out
    hipLaunchKernelGGL(gather2_kernel, dim3((N + 3) / 4), dim3(256), 0, stream,
                       STARTS, EID, dst, COEF2, S2, bias_c, out, N);
}

// Round 3
// 562.810 us; speedup vs baseline: 2.4010x; 1.3815x over previous
//
#include <hip/hip_runtime.h>
#include <hip/hip_bf16.h>
#include <cstddef>
#include <cstdint>

#define IN_DIM 512
#define R_DIM 128
#define F_DIM 64
#define H_NUM 4
#define OUT_DIM 64
#define HF 256  // H_NUM * F_DIM

typedef __attribute__((ext_vector_type(4))) float f32x4;
typedef __attribute__((ext_vector_type(8))) short bf16x8;

typedef const __attribute__((address_space(1))) void gas_void;
typedef __attribute__((address_space(3))) void las_void;

__device__ __forceinline__ float bf2f(ushort u) {
    union { uint i; float f; } v; v.i = ((uint)u) << 16; return v.f;
}
__device__ __forceinline__ ushort f2bf(float f) {
    union { float f; uint i; } v; v.f = f;
    uint r = v.i + 0x7fff + ((v.i >> 16) & 1);
    return (ushort)(r >> 16);
}

// ---------------------------------------------------------------- zero ints
__global__ __launch_bounds__(256) void zero_i32(int* __restrict__ p, int n) {
    int i = blockIdx.x * 256 + threadIdx.x;
    if (i < n) p[i] = 0;
}

// ------------------------------------------------------- fp32 -> bf16 (x8)
__global__ __launch_bounds__(256) void f2bf_kernel(const float* __restrict__ in,
                                                   ushort* __restrict__ out, int n8) {
    int i = blockIdx.x * 256 + threadIdx.x;
    if (i >= n8) return;
    const float4* p = (const float4*)in + (size_t)i * 2;
    float4 a = p[0], b = p[1];
    ushort us[8] = {f2bf(a.x), f2bf(a.y), f2bf(a.z), f2bf(a.w),
                    f2bf(b.x), f2bf(b.y), f2bf(b.z), f2bf(b.w)};
    *(uint4*)(out + (size_t)i * 8) = *(const uint4*)us;
}

// ------------------------------------------------- fold W_seq @ W_lin (heads)
__global__ __launch_bounds__(256) void wcomb1_kernel(const float* __restrict__ Wlin,
                                                     const float* __restrict__ Wseq,
                                                     ushort* __restrict__ Wc) {
    int idx = blockIdx.x * 256 + threadIdx.x;
    if (idx >= H_NUM * F_DIM * IN_DIM) return;
    int i  = idx & (IN_DIM - 1);
    int hf = idx >> 9;          // h*64 + f
    int h  = hf >> 6;
    const float* ws = Wseq + (size_t)hf * R_DIM;
    const float* wl = Wlin + (size_t)h * R_DIM * IN_DIM + i;
    float acc = 0.0f;
#pragma unroll 8
    for (int r = 0; r < R_DIM; ++r) acc += ws[r] * wl[(size_t)r * IN_DIM];
    Wc[idx] = f2bf(acc);
}

// ---------------------------------------------- fold W_seq_c @ W_lin_c (clf)
__global__ __launch_bounds__(256) void wcomb2_kernel(const float* __restrict__ Wlin,
                                                     const float* __restrict__ Wseq,
                                                     ushort* __restrict__ Wc) {
    int idx = blockIdx.x * 256 + threadIdx.x;
    if (idx >= OUT_DIM * HF) return;
    int j = idx & (HF - 1);
    int o = idx >> 8;
    const float* ws = Wseq + (size_t)o * R_DIM;
    const float* wl = Wlin + j;
    float acc = 0.0f;
#pragma unroll 8
    for (int r = 0; r < R_DIM; ++r) acc += ws[r] * wl[(size_t)r * HF];
    Wc[idx] = f2bf(acc);
}

// --------------------------------------------------------- bf16 MFMA GEMM TN
// C[m][n] = sum_k A[m][k] * B[n][k]; A [M][K] bf16, B [Ntot][K] bf16, C bf16.
// BM=128, BK=64, 256 threads (4 waves), wave w owns rows w*32..w*32+31.
// LDS XOR-swizzle (chunk ^= row&7) applied on reads; global source pre-swizzled
// so global_load_lds (linear LDS dest) lands data where the reads expect it.
template<int BN, int K>
__global__ __launch_bounds__(256) void gemm_bf16(const ushort* __restrict__ A,
                                                 const ushort* __restrict__ B,
                                                 ushort* __restrict__ C,
                                                 int M, int Ntot) {
    constexpr int NF = BN / 16;
    __shared__ ushort As[128 * 64];
    __shared__ ushort Bs[BN * 64];
    const int tid = threadIdx.x;
    const int wave = tid >> 6;
    const int lane = tid & 63;
    const int lr = lane & 15;   // fragment row (A) / col (B)
    const int lg = lane >> 4;   // k-group
    const int m0 = blockIdx.x * 128;
    const int n0 = blockIdx.y * BN;

    // LDS read byte offsets (constant per thread)
    int aoff[2][2], boff[NF][2];
#pragma unroll
    for (int rb = 0; rb < 2; ++rb)
#pragma unroll
        for (int ks = 0; ks < 2; ++ks) {
            int row = wave * 32 + rb * 16 + lr;
            int c = ks * 4 + lg;
            aoff[rb][ks] = row * 128 + ((c ^ (row & 7)) * 16);
        }
#pragma unroll
    for (int cb = 0; cb < NF; ++cb)
#pragma unroll
        for (int ks = 0; ks < 2; ++ks) {
            int row = cb * 16 + lr;
            int c = ks * 4 + lg;
            boff[cb][ks] = row * 128 + ((c ^ (row & 7)) * 16);
        }

    f32x4 acc[2][NF];
#pragma unroll
    for (int rb = 0; rb < 2; ++rb)
#pragma unroll
        for (int cb = 0; cb < NF; ++cb) acc[rb][cb] = (f32x4)0.0f;

    for (int k0 = 0; k0 < K; k0 += 64) {
        // stage A tile (16 KB): 4 rounds x 256 threads x 16 B
#pragma unroll
        for (int r = 0; r < 4; ++r) {
            int off = r * 4096 + tid * 16;
            int row = off >> 7;
            int kch = ((off >> 4) & 7) ^ (row & 7);
            const ushort* g = A + (size_t)(m0 + row) * K + k0 + kch * 8;
            __builtin_amdgcn_global_load_lds((gas_void*)g,
                                             (las_void*)((char*)As + off), 16, 0, 0);
        }
        // stage B tile
#pragma unroll
        for (int r = 0; r < BN / 32; ++r) {
            int off = r * 4096 + tid * 16;
            int row = off >> 7;
            int kch = ((off >> 4) & 7) ^ (row & 7);
            const ushort* g = B + (size_t)(n0 + row) * K + k0 + kch * 8;
            __builtin_amdgcn_global_load_lds((gas_void*)g,
                                             (las_void*)((char*)Bs + off), 16, 0, 0);
        }
        __syncthreads();   // drains vmcnt before barrier
#pragma unroll
        for (int ks = 0; ks < 2; ++ks) {
            bf16x8 af[2], bfr[NF];
#pragma unroll
            for (int rb = 0; rb < 2; ++rb)
                af[rb] = *(const bf16x8*)((const char*)As + aoff[rb][ks]);
#pragma unroll
            for (int cb = 0; cb < NF; ++cb)
                bfr[cb] = *(const bf16x8*)((const char*)Bs + boff[cb][ks]);
#pragma unroll
            for (int rb = 0; rb < 2; ++rb)
#pragma unroll
                for (int cb = 0; cb < NF; ++cb)
                    acc[rb][cb] = __builtin_amdgcn_mfma_f32_16x16x32_bf16(
                        af[rb], bfr[cb], acc[rb][cb], 0, 0, 0);
        }
        __syncthreads();
    }

    // C/D layout: col = lane&15, row = (lane>>4)*4 + reg  [m89/m91 verified]
#pragma unroll
    for (int rb = 0; rb < 2; ++rb) {
        int rowb = m0 + wave * 32 + rb * 16 + lg * 4;
#pragma unroll
        for (int cb = 0; cb < NF; ++cb) {
            int col = n0 + cb * 16 + lr;
#pragma unroll
            for (int r = 0; r < 4; ++r) {
                int row = rowb + r;
                if (row < M) C[(size_t)row * Ntot + col] = f2bf(acc[rb][cb][r]);
            }
        }
    }
}

// ------------------------------------------- f1/f2 dots, heads layer (wave/nh)
__global__ __launch_bounds__(256) void fvec_h_kernel(const ushort* __restrict__ S,
                                                     const float* __restrict__ a1,
                                                     const float* __restrict__ b1,
                                                     const float* __restrict__ a2,
                                                     const float* __restrict__ b2,
                                                     float* __restrict__ f1,
                                                     float* __restrict__ f2,
                                                     int NH) {
    int w = (int)((blockIdx.x * blockDim.x + threadIdx.x) >> 6);
    int lane = threadIdx.x & 63;
    if (w >= NH) return;
    int n = w >> 2;
    int h = w & 3;
    float s = bf2f(S[(size_t)n * HF + h * 64 + lane]);
    float p1 = s * a1[h * 64 + lane];
    float p2 = s * a2[h * 64 + lane];
#pragma unroll
    for (int off = 32; off > 0; off >>= 1) {
        p1 += __shfl_down(p1, off, 64);
        p2 += __shfl_down(p2, off, 64);
    }
    if (lane == 0) {
        f1[w] = p1 + b1[h];
        f2[w] = p2 + b2[h];
    }
}

// ------------------------------------------- f1/f2 dots, classifier (wave/n)
__global__ __launch_bounds__(256) void fvec_c_kernel(const ushort* __restrict__ S,
                                                     const float* __restrict__ a1,
                                                     const float* __restrict__ b1,
                                                     const float* __restrict__ a2,
                                                     const float* __restrict__ b2,
                                                     float* __restrict__ f1,
                                                     float* __restrict__ f2,
                                                     int N) {
    int w = (int)((blockIdx.x * blockDim.x + threadIdx.x) >> 6);
    int lane = threadIdx.x & 63;
    if (w >= N) return;
    float s = bf2f(S[(size_t)w * OUT_DIM + lane]);
    float p1 = s * a1[lane];
    float p2 = s * a2[lane];
#pragma unroll
    for (int off = 32; off > 0; off >>= 1) {
        p1 += __shfl_down(p1, off, 64);
        p2 += __shfl_down(p2, off, 64);
    }
    if (lane == 0) {
        f1[w] = p1 + b1[0];
        f2[w] = p2 + b2[0];
    }
}

// ------------------------------------------------------------ CSR: histogram
__global__ __launch_bounds__(256) void hist_kernel(const int* __restrict__ src,
                                                   int* __restrict__ counts, int E) {
    int e = blockIdx.x * 256 + threadIdx.x;
    if (e < E) atomicAdd(&counts[src[e]], 1);
}

// -------------------------------------------- CSR: single-block chunked scan
__global__ __launch_bounds__(1024) void scan_kernel(const int* __restrict__ counts,
                                                    int* __restrict__ starts,
                                                    int* __restrict__ cursor, int N) {
    __shared__ int buf[1024];
    __shared__ int carry_s;
    int tid = threadIdx.x;
    if (tid == 0) carry_s = 0;
    __syncthreads();
    for (int base = 0; base < N; base += 1024) {
        int v = (base + tid < N) ? counts[base + tid] : 0;
        buf[tid] = v;
        __syncthreads();
#pragma unroll
        for (int off = 1; off < 1024; off <<= 1) {
            int t = (tid >= off) ? buf[tid - off] : 0;
            __syncthreads();
            buf[tid] += t;
            __syncthreads();
        }
        int carry = carry_s;
        int excl = carry + buf[tid] - v;
        if (base + tid < N) {
            starts[base + tid] = excl;
            cursor[base + tid] = excl;
        }
        __syncthreads();
        if (tid == 0) carry_s = carry + buf[1023];
        __syncthreads();
    }
    if (tid == 0) starts[N] = carry_s;
}

// ----------------------------------------------------- CSR: position scatter
__global__ __launch_bounds__(256) void scatter_kernel(const int* __restrict__ src,
                                                      int* __restrict__ cursor,
                                                      int* __restrict__ eid, int E) {
    int e = blockIdx.x * 256 + threadIdx.x;
    if (e >= E) return;
    int p = atomicAdd(&cursor[src[e]], 1);
    eid[p] = e;
}

// --------------------------------------------- per-edge coefs, heads (4/edge)
__global__ __launch_bounds__(256) void coef1_kernel(const int* __restrict__ src,
                                                    const int* __restrict__ dst,
                                                    const float* __restrict__ f1,
                                                    const float* __restrict__ f2,
                                                    float4* __restrict__ coef, int E) {
    int e = blockIdx.x * 256 + threadIdx.x;
    if (e >= E) return;
    int s = src[e], d = dst[e];
    float4 l1 = *(const float4*)(f1 + (size_t)s * 4);
    float4 l2 = *(const float4*)(f2 + (size_t)d * 4);
    float lx = l1.x + l2.x, ly = l1.y + l2.y, lz = l1.z + l2.z, lw = l1.w + l2.w;
    lx = lx > 0.f ? lx : 0.2f * lx;
    ly = ly > 0.f ? ly : 0.2f * ly;
    lz = lz > 0.f ? lz : 0.2f * lz;
    lw = lw > 0.f ? lw : 0.2f * lw;
    coef[e] = make_float4(expf(lx), expf(ly), expf(lz), expf(lw));
}

// ------------------------------------------------ per-edge coef, classifier
__global__ __launch_bounds__(256) void coef2_kernel(const int* __restrict__ src,
                                                    const int* __restrict__ dst,
                                                    const float* __restrict__ f1,
                                                    const float* __restrict__ f2,
                                                    float* __restrict__ coef, int E) {
    int e = blockIdx.x * 256 + threadIdx.x;
    if (e >= E) return;
    float l = f1[src[e]] + f2[dst[e]];
    l = l > 0.f ? l : 0.2f * l;
    coef[e] = expf(l);
}

// ----------------------- gather + normalize + bias + ELU, heads (wave/node)
__global__ __launch_bounds__(256) void gather1_kernel(const int* __restrict__ starts,
                                                      const int* __restrict__ eid,
                                                      const int* __restrict__ dst,
                                                      const float4* __restrict__ coef,
                                                      const ushort* __restrict__ S1,
                                                      const float* __restrict__ bias,
                                                      ushort* __restrict__ hcat, int N) {
    int n = (int)((blockIdx.x * blockDim.x + threadIdx.x) >> 6);
    int lane = threadIdx.x & 63;
    if (n >= N) return;
    int beg = starts[n], end = starts[n + 1];
    float a0 = 0.f, a1 = 0.f, a2 = 0.f, a3 = 0.f;
    float d0 = 0.f, d1 = 0.f, d2 = 0.f, d3 = 0.f;
    for (int i = beg; i < end; ++i) {
        int e = eid[i];
        int d = dst[e];
        float4 c = coef[e];
        const ushort* row = S1 + (size_t)d * HF;
        a0 += c.x * bf2f(row[lane]);
        a1 += c.y * bf2f(row[64 + lane]);
        a2 += c.z * bf2f(row[128 + lane]);
        a3 += c.w * bf2f(row[192 + lane]);
        d0 += c.x; d1 += c.y; d2 += c.z; d3 += c.w;
    }
    ushort* orow = hcat + (size_t)n * HF;
    float v0 = a0 / d0 + bias[lane];
    float v1 = a1 / d1 + bias[64 + lane];
    float v2 = a2 / d2 + bias[128 + lane];
    float v3 = a3 / d3 + bias[192 + lane];
    orow[lane]       = f2bf(v0 > 0.f ? v0 : expm1f(v0));
    orow[64 + lane]  = f2bf(v1 > 0.f ? v1 : expm1f(v1));
    orow[128 + lane] = f2bf(v2 > 0.f ? v2 : expm1f(v2));
    orow[192 + lane] = f2bf(v3 > 0.f ? v3 : expm1f(v3));
}

// --------------------------- gather + normalize + bias, classifier (wave/node)
__global__ __launch_bounds__(256) void gather2_kernel(const int* __restrict__ starts,
                                                      const int* __restrict__ eid,
                                                      const int* __restrict__ dst,
                                                      const float* __restrict__ coef,
                                                      const ushort* __restrict__ S2,
                                                      const float* __restrict__ bias,
                                                      float* __restrict__ out, int N) {
    int n = (int)((blockIdx.x * blockDim.x + threadIdx.x) >> 6);
    int lane = threadIdx.x & 63;
    if (n >= N) return;
    int beg = starts[n], end = starts[n + 1];
    float acc = 0.f, den = 0.f;
    for (int i = beg; i < end; ++i) {
        int e = eid[i];
        int d = dst[e];
        float c = coef[e];
        acc += c * bf2f(S2[(size_t)d * OUT_DIM + lane]);
        den += c;
    }
    out[(size_t)n * OUT_DIM + lane] = acc / den + bias[lane];
}

// ===========================================================================
extern "C" void kernel_launch(void* const* d_in, const int* in_sizes, int n_in,
                              void* d_out, int out_size, void* d_ws, size_t ws_size,
                              hipStream_t stream) {
    const float* x      = (const float*)d_in[0];
    const int*   edges  = (const int*)d_in[1];
    const float* Wlin_h = (const float*)d_in[2];
    const float* Wseq_h = (const float*)d_in[3];
    const float* a1_h   = (const float*)d_in[4];
    const float* b1_h   = (const float*)d_in[5];
    const float* a2_h   = (const float*)d_in[6];
    const float* b2_h   = (const float*)d_in[7];
    const float* bias_h = (const float*)d_in[8];
    const float* Wlin_c = (const float*)d_in[9];
    const float* Wseq_c = (const float*)d_in[10];
    const float* a1_c   = (const float*)d_in[11];
    const float* b1_c   = (const float*)d_in[12];
    const float* a2_c   = (const float*)d_in[13];
    const float* b2_c   = (const float*)d_in[14];
    const float* bias_c = (const float*)d_in[15];

    const int N = in_sizes[0] / IN_DIM;
    const int E = in_sizes[1] / 2;
    const int* src = edges;
    const int* dst = edges + E;

    char* ws = (char*)d_ws;
    size_t off = 0;
    ushort* XB    = (ushort*)(ws + off); off += (size_t)N * IN_DIM * 2;        // 51.2 MB
    ushort* WC1   = (ushort*)(ws + off); off += (size_t)HF * IN_DIM * 2;       // 256 KB
    ushort* WC2   = (ushort*)(ws + off); off += (size_t)OUT_DIM * HF * 2;      // 32 KB
    ushort* S1    = (ushort*)(ws + off); off += (size_t)N * HF * 2;            // 25.6 MB
    ushort* S2    = S1;  // S1 dead after gather1; reuse for S2 [N][64]
    ushort* HCAT  = (ushort*)(ws + off); off += (size_t)N * HF * 2;            // 25.6 MB
    float*  COEF1 = (float*)(ws + off);  off += (size_t)E * 4 * 4;             // 12.8 MB
    float*  COEF2 = COEF1;
    float*  F1    = (float*)(ws + off);  off += (size_t)N * H_NUM * 4;
    float*  F2    = (float*)(ws + off);  off += (size_t)N * H_NUM * 4;
    float*  F1c   = (float*)(ws + off);  off += (size_t)N * 4;
    float*  F2c   = (float*)(ws + off);  off += (size_t)N * 4;
    int* COUNTS   = (int*)(ws + off);    off += (size_t)N * 4;
    int* STARTS   = (int*)(ws + off);    off += ((size_t)N + 1) * 4;
    int* CURSOR   = (int*)(ws + off);    off += (size_t)N * 4;
    int* EID      = (int*)(ws + off);    off += (size_t)E * 4;

    float* out = (float*)d_out;

    const int eg = (E + 255) / 256;
    const int ng = (N + 255) / 256;

    // ---- CSR build (shared by both layers)
    hipLaunchKernelGGL(zero_i32, dim3(ng), dim3(256), 0, stream, COUNTS, N);
    hipLaunchKernelGGL(hist_kernel, dim3(eg), dim3(256), 0, stream, src, COUNTS, E);
    hipLaunchKernelGGL(scan_kernel, dim3(1), dim3(1024), 0, stream, COUNTS, STARTS, CURSOR, N);
    hipLaunchKernelGGL(scatter_kernel, dim3(eg), dim3(256), 0, stream, src, CURSOR, EID, E);

    // ---- convert x to bf16; fold weights (bf16 out)
    hipLaunchKernelGGL(f2bf_kernel, dim3((N * IN_DIM / 8 + 255) / 256), dim3(256), 0, stream,
                       x, XB, N * IN_DIM / 8);
    hipLaunchKernelGGL(wcomb1_kernel, dim3((HF * IN_DIM + 255) / 256), dim3(256),
                       0, stream, Wlin_h, Wseq_h, WC1);
    hipLaunchKernelGGL(wcomb2_kernel, dim3((OUT_DIM * HF + 255) / 256), dim3(256),
                       0, stream, Wlin_c, Wseq_c, WC2);

    // ---- layer 1: S1 = x @ Wc1^T   [N,512] x [256,512] -> [N,256] bf16
    hipLaunchKernelGGL((gemm_bf16<128, IN_DIM>), dim3((N + 127) / 128, HF / 128), dim3(256),
                       0, stream, XB, WC1, S1, N, HF);

    // ---- f1/f2 per (node, head), per-edge coefs
    hipLaunchKernelGGL(fvec_h_kernel, dim3((N * H_NUM + 3) / 4), dim3(256), 0, stream,
                       S1, a1_h, b1_h, a2_h, b2_h, F1, F2, N * H_NUM);
    hipLaunchKernelGGL(coef1_kernel, dim3(eg), dim3(256), 0, stream,
                       src, dst, F1, F2, (float4*)COEF1, E);

    // ---- gather layer 1 (fused normalize + bias + ELU) -> HCAT bf16
    hipLaunchKernelGGL(gather1_kernel, dim3((N + 3) / 4), dim3(256), 0, stream,
                       STARTS, EID, dst, (const float4*)COEF1, S1, bias_h, HCAT, N);

    // ---- classifier: S2 = hcat @ Wc2^T   [N,256] x [64,256] -> [N,64] bf16
    hipLaunchKernelGGL((gemm_bf16<64, HF>), dim3((N + 127) / 128, 1), dim3(256),
                       0, stream, HCAT, WC2, S2, N, OUT_DIM);

    // ---- f1/f2 classifier, per-edge coefs
    hipLaunchKernelGGL(fvec_c_kernel, dim3((N + 3) / 4), dim3(256), 0, stream,
                       S2, a1_c, b1_c, a2_c, b2_c, F1c, F2c, N);
    hipLaunchKernelGGL(coef2_kernel, dim3(eg), dim3(256), 0, stream,
                       src, dst, F1c, F2c, COEF2, E);

    // ---- gather classifier (fused normalize + bias) -> out fp32
    hipLaunchKernelGGL(gather2_kernel, dim3((N + 3) / 4), dim3(256), 0, stream,
                       STARTS, EID, dst, COEF2, S2, bias_c, out, N);
}

// Round 4
// 363.076 us; speedup vs baseline: 3.7218x; 1.5501x over previous
//
#include <hip/hip_runtime.h>
#include <hip/hip_bf16.h>
#include <cstddef>
#include <cstdint>

#define IN_DIM 512
#define R_DIM 128
#define F_DIM 64
#define H_NUM 4
#define OUT_DIM 64
#define HF 256  // H_NUM * F_DIM

typedef __attribute__((ext_vector_type(4))) float f32x4;
typedef __attribute__((ext_vector_type(8))) short bf16x8;

typedef const __attribute__((address_space(1))) void gas_void;
typedef __attribute__((address_space(3))) void las_void;

__device__ __forceinline__ float bf2f(ushort u) {
    union { uint i; float f; } v; v.i = ((uint)u) << 16; return v.f;
}
__device__ __forceinline__ ushort f2bf(float f) {
    union { float f; uint i; } v; v.f = f;
    uint r = v.i + 0x7fff + ((v.i >> 16) & 1);
    return (ushort)(r >> 16);
}

// ---------------------------------------------------------------- zero ints
__global__ __launch_bounds__(256) void zero_i32(int* __restrict__ p, int n) {
    int i = blockIdx.x * 256 + threadIdx.x;
    if (i < n) p[i] = 0;
}

// ------------------------------------------------------- fp32 -> bf16 (x8)
__global__ __launch_bounds__(256) void f2bf_kernel(const float* __restrict__ in,
                                                   ushort* __restrict__ out, int n8) {
    int i = blockIdx.x * 256 + threadIdx.x;
    if (i >= n8) return;
    const float4* p = (const float4*)in + (size_t)i * 2;
    float4 a = p[0], b = p[1];
    ushort us[8] = {f2bf(a.x), f2bf(a.y), f2bf(a.z), f2bf(a.w),
                    f2bf(b.x), f2bf(b.y), f2bf(b.z), f2bf(b.w)};
    *(uint4*)(out + (size_t)i * 8) = *(const uint4*)us;
}

// ------------------------------------------------- fold W_seq @ W_lin (heads)
__global__ __launch_bounds__(256) void wcomb1_kernel(const float* __restrict__ Wlin,
                                                     const float* __restrict__ Wseq,
                                                     ushort* __restrict__ Wc) {
    int idx = blockIdx.x * 256 + threadIdx.x;
    if (idx >= H_NUM * F_DIM * IN_DIM) return;
    int i  = idx & (IN_DIM - 1);
    int hf = idx >> 9;          // h*64 + f
    int h  = hf >> 6;
    const float* ws = Wseq + (size_t)hf * R_DIM;
    const float* wl = Wlin + (size_t)h * R_DIM * IN_DIM + i;
    float acc = 0.0f;
#pragma unroll 8
    for (int r = 0; r < R_DIM; ++r) acc += ws[r] * wl[(size_t)r * IN_DIM];
    Wc[idx] = f2bf(acc);
}

// ---------------------------------------------- fold W_seq_c @ W_lin_c (clf)
__global__ __launch_bounds__(256) void wcomb2_kernel(const float* __restrict__ Wlin,
                                                     const float* __restrict__ Wseq,
                                                     ushort* __restrict__ Wc) {
    int idx = blockIdx.x * 256 + threadIdx.x;
    if (idx >= OUT_DIM * HF) return;
    int j = idx & (HF - 1);
    int o = idx >> 8;
    const float* ws = Wseq + (size_t)o * R_DIM;
    const float* wl = Wlin + j;
    float acc = 0.0f;
#pragma unroll 8
    for (int r = 0; r < R_DIM; ++r) acc += ws[r] * wl[(size_t)r * HF];
    Wc[idx] = f2bf(acc);
}

// --------------------------------------------------------- bf16 MFMA GEMM TN
// C[m][n] = sum_k A[m][k] * B[n][k]; A [M][K] bf16, B [Ntot][K] bf16, C bf16.
template<int BN, int K>
__global__ __launch_bounds__(256) void gemm_bf16(const ushort* __restrict__ A,
                                                 const ushort* __restrict__ B,
                                                 ushort* __restrict__ C,
                                                 int M, int Ntot) {
    constexpr int NF = BN / 16;
    __shared__ ushort As[128 * 64];
    __shared__ ushort Bs[BN * 64];
    const int tid = threadIdx.x;
    const int wave = tid >> 6;
    const int lane = tid & 63;
    const int lr = lane & 15;   // fragment row (A) / col (B)
    const int lg = lane >> 4;   // k-group
    const int m0 = blockIdx.x * 128;
    const int n0 = blockIdx.y * BN;

    int aoff[2][2], boff[NF][2];
#pragma unroll
    for (int rb = 0; rb < 2; ++rb)
#pragma unroll
        for (int ks = 0; ks < 2; ++ks) {
            int row = wave * 32 + rb * 16 + lr;
            int c = ks * 4 + lg;
            aoff[rb][ks] = row * 128 + ((c ^ (row & 7)) * 16);
        }
#pragma unroll
    for (int cb = 0; cb < NF; ++cb)
#pragma unroll
        for (int ks = 0; ks < 2; ++ks) {
            int row = cb * 16 + lr;
            int c = ks * 4 + lg;
            boff[cb][ks] = row * 128 + ((c ^ (row & 7)) * 16);
        }

    f32x4 acc[2][NF];
#pragma unroll
    for (int rb = 0; rb < 2; ++rb)
#pragma unroll
        for (int cb = 0; cb < NF; ++cb) acc[rb][cb] = (f32x4)0.0f;

    for (int k0 = 0; k0 < K; k0 += 64) {
#pragma unroll
        for (int r = 0; r < 4; ++r) {
            int off = r * 4096 + tid * 16;
            int row = off >> 7;
            int kch = ((off >> 4) & 7) ^ (row & 7);
            const ushort* g = A + (size_t)(m0 + row) * K + k0 + kch * 8;
            __builtin_amdgcn_global_load_lds((gas_void*)g,
                                             (las_void*)((char*)As + off), 16, 0, 0);
        }
#pragma unroll
        for (int r = 0; r < BN / 32; ++r) {
            int off = r * 4096 + tid * 16;
            int row = off >> 7;
            int kch = ((off >> 4) & 7) ^ (row & 7);
            const ushort* g = B + (size_t)(n0 + row) * K + k0 + kch * 8;
            __builtin_amdgcn_global_load_lds((gas_void*)g,
                                             (las_void*)((char*)Bs + off), 16, 0, 0);
        }
        __syncthreads();
#pragma unroll
        for (int ks = 0; ks < 2; ++ks) {
            bf16x8 af[2], bfr[NF];
#pragma unroll
            for (int rb = 0; rb < 2; ++rb)
                af[rb] = *(const bf16x8*)((const char*)As + aoff[rb][ks]);
#pragma unroll
            for (int cb = 0; cb < NF; ++cb)
                bfr[cb] = *(const bf16x8*)((const char*)Bs + boff[cb][ks]);
#pragma unroll
            for (int rb = 0; rb < 2; ++rb)
#pragma unroll
                for (int cb = 0; cb < NF; ++cb)
                    acc[rb][cb] = __builtin_amdgcn_mfma_f32_16x16x32_bf16(
                        af[rb], bfr[cb], acc[rb][cb], 0, 0, 0);
        }
        __syncthreads();
    }

#pragma unroll
    for (int rb = 0; rb < 2; ++rb) {
        int rowb = m0 + wave * 32 + rb * 16 + lg * 4;
#pragma unroll
        for (int cb = 0; cb < NF; ++cb) {
            int col = n0 + cb * 16 + lr;
#pragma unroll
            for (int r = 0; r < 4; ++r) {
                int row = rowb + r;
                if (row < M) C[(size_t)row * Ntot + col] = f2bf(acc[rb][cb][r]);
            }
        }
    }
}

// ------------------------------------------- f1/f2 dots, heads layer (wave/nh)
__global__ __launch_bounds__(256) void fvec_h_kernel(const ushort* __restrict__ S,
                                                     const float* __restrict__ a1,
                                                     const float* __restrict__ b1,
                                                     const float* __restrict__ a2,
                                                     const float* __restrict__ b2,
                                                     float* __restrict__ f1,
                                                     float* __restrict__ f2,
                                                     int NH) {
    int w = (int)((blockIdx.x * blockDim.x + threadIdx.x) >> 6);
    int lane = threadIdx.x & 63;
    if (w >= NH) return;
    int n = w >> 2;
    int h = w & 3;
    float s = bf2f(S[(size_t)n * HF + h * 64 + lane]);
    float p1 = s * a1[h * 64 + lane];
    float p2 = s * a2[h * 64 + lane];
#pragma unroll
    for (int off = 32; off > 0; off >>= 1) {
        p1 += __shfl_down(p1, off, 64);
        p2 += __shfl_down(p2, off, 64);
    }
    if (lane == 0) {
        f1[w] = p1 + b1[h];
        f2[w] = p2 + b2[h];
    }
}

// ------------------------------------------- f1/f2 dots, classifier (wave/n)
__global__ __launch_bounds__(256) void fvec_c_kernel(const ushort* __restrict__ S,
                                                     const float* __restrict__ a1,
                                                     const float* __restrict__ b1,
                                                     const float* __restrict__ a2,
                                                     const float* __restrict__ b2,
                                                     float* __restrict__ f1,
                                                     float* __restrict__ f2,
                                                     int N) {
    int w = (int)((blockIdx.x * blockDim.x + threadIdx.x) >> 6);
    int lane = threadIdx.x & 63;
    if (w >= N) return;
    float s = bf2f(S[(size_t)w * OUT_DIM + lane]);
    float p1 = s * a1[lane];
    float p2 = s * a2[lane];
#pragma unroll
    for (int off = 32; off > 0; off >>= 1) {
        p1 += __shfl_down(p1, off, 64);
        p2 += __shfl_down(p2, off, 64);
    }
    if (lane == 0) {
        f1[w] = p1 + b1[0];
        f2[w] = p2 + b2[0];
    }
}

// ------------------------------------------------------------ CSR: histogram
__global__ __launch_bounds__(256) void hist_kernel(const int* __restrict__ src,
                                                   int* __restrict__ counts, int E) {
    int e = blockIdx.x * 256 + threadIdx.x;
    if (e < E) atomicAdd(&counts[src[e]], 1);
}

// ----------------------------------------- scan stage 1: per-block excl scan
__global__ __launch_bounds__(256) void scan_blk(const int* __restrict__ counts,
                                                int* __restrict__ lexcl,
                                                int* __restrict__ part, int N) {
    __shared__ int wsum[4];
    int t = threadIdx.x;
    int g = blockIdx.x * 256 + t;
    int lane = t & 63, wid = t >> 6;
    int v = (g < N) ? counts[g] : 0;
    int x = v;
#pragma unroll
    for (int off = 1; off < 64; off <<= 1) {
        int u = __shfl_up(x, off, 64);
        if (lane >= off) x += u;
    }
    if (lane == 63) wsum[wid] = x;
    __syncthreads();
    int woff = 0;
#pragma unroll
    for (int w = 0; w < 3; ++w) if (w < wid) woff += wsum[w];
    int incl = x + woff;
    if (g < N) lexcl[g] = incl - v;
    if (t == 255) part[blockIdx.x] = incl;
}

// --------------------------------- scan stage 2: excl scan of block partials
__global__ __launch_bounds__(256) void scan_part(int* __restrict__ part, int nb) {
    __shared__ int wsum[4];
    int t = threadIdx.x;
    int lane = t & 63, wid = t >> 6;
    int v = (t < nb) ? part[t] : 0;
    int x = v;
#pragma unroll
    for (int off = 1; off < 64; off <<= 1) {
        int u = __shfl_up(x, off, 64);
        if (lane >= off) x += u;
    }
    if (lane == 63) wsum[wid] = x;
    __syncthreads();
    int woff = 0;
#pragma unroll
    for (int w = 0; w < 3; ++w) if (w < wid) woff += wsum[w];
    int incl = x + woff;
    __syncthreads();
    if (t < nb) part[t] = incl - v;
    if (t == 255) part[nb] = incl;   // grand total
}

// ------------------------------------- scan stage 3: add offsets, emit CSR ptrs
__global__ __launch_bounds__(256) void scan_add(const int* __restrict__ lexcl,
                                                const int* __restrict__ part,
                                                int* __restrict__ starts,
                                                int* __restrict__ cursor, int N, int nb) {
    int g = blockIdx.x * 256 + threadIdx.x;
    if (g < N) {
        int s = lexcl[g] + part[blockIdx.x];
        starts[g] = s;
        cursor[g] = s;
    }
    if (g == 0) starts[N] = part[nb];
}

// ----------------------------------------------------- CSR: position scatter
__global__ __launch_bounds__(256) void scatter_kernel(const int* __restrict__ src,
                                                      int* __restrict__ cursor,
                                                      int* __restrict__ eid, int E) {
    int e = blockIdx.x * 256 + threadIdx.x;
    if (e >= E) return;
    int p = atomicAdd(&cursor[src[e]], 1);
    eid[p] = e;
}

// --------------------------------------------- per-edge coefs, heads (4/edge)
__global__ __launch_bounds__(256) void coef1_kernel(const int* __restrict__ src,
                                                    const int* __restrict__ dst,
                                                    const float* __restrict__ f1,
                                                    const float* __restrict__ f2,
                                                    float4* __restrict__ coef, int E) {
    int e = blockIdx.x * 256 + threadIdx.x;
    if (e >= E) return;
    int s = src[e], d = dst[e];
    float4 l1 = *(const float4*)(f1 + (size_t)s * 4);
    float4 l2 = *(const float4*)(f2 + (size_t)d * 4);
    float lx = l1.x + l2.x, ly = l1.y + l2.y, lz = l1.z + l2.z, lw = l1.w + l2.w;
    lx = lx > 0.f ? lx : 0.2f * lx;
    ly = ly > 0.f ? ly : 0.2f * ly;
    lz = lz > 0.f ? lz : 0.2f * lz;
    lw = lw > 0.f ? lw : 0.2f * lw;
    coef[e] = make_float4(expf(lx), expf(ly), expf(lz), expf(lw));
}

// ------------------------------------------------ per-edge coef, classifier
__global__ __launch_bounds__(256) void coef2_kernel(const int* __restrict__ src,
                                                    const int* __restrict__ dst,
                                                    const float* __restrict__ f1,
                                                    const float* __restrict__ f2,
                                                    float* __restrict__ coef, int E) {
    int e = blockIdx.x * 256 + threadIdx.x;
    if (e >= E) return;
    float l = f1[src[e]] + f2[dst[e]];
    l = l > 0.f ? l : 0.2f * l;
    coef[e] = expf(l);
}

// ----------------------- gather + normalize + bias + ELU, heads (wave/node)
// lane owns flattened features lane*4..lane*4+3 (all in head lane>>4):
// one ushort4 row load per edge; x4 edge unroll for MLP.
__global__ __launch_bounds__(256) void gather1_kernel(const int* __restrict__ starts,
                                                      const int* __restrict__ eid,
                                                      const int* __restrict__ dst,
                                                      const float* __restrict__ coef,
                                                      const ushort* __restrict__ S1,
                                                      const float* __restrict__ bias,
                                                      ushort* __restrict__ hcat, int N) {
    int n = (int)((blockIdx.x * blockDim.x + threadIdx.x) >> 6);
    int lane = threadIdx.x & 63;
    if (n >= N) return;
    const int head = lane >> 4;
    int beg = starts[n], end = starts[n + 1];
    float a0 = 0.f, a1 = 0.f, a2 = 0.f, a3 = 0.f, den = 0.f;
    int i = beg;
    for (; i + 4 <= end; i += 4) {
        int e0 = eid[i], e1 = eid[i + 1], e2 = eid[i + 2], e3 = eid[i + 3];
        int d0 = dst[e0], d1 = dst[e1], d2 = dst[e2], d3 = dst[e3];
        float c0 = coef[(size_t)e0 * 4 + head];
        float c1 = coef[(size_t)e1 * 4 + head];
        float c2 = coef[(size_t)e2 * 4 + head];
        float c3 = coef[(size_t)e3 * 4 + head];
        ushort4 r0 = *(const ushort4*)(S1 + (size_t)d0 * HF + lane * 4);
        ushort4 r1 = *(const ushort4*)(S1 + (size_t)d1 * HF + lane * 4);
        ushort4 r2 = *(const ushort4*)(S1 + (size_t)d2 * HF + lane * 4);
        ushort4 r3 = *(const ushort4*)(S1 + (size_t)d3 * HF + lane * 4);
        a0 += c0 * bf2f(r0.x); a1 += c0 * bf2f(r0.y); a2 += c0 * bf2f(r0.z); a3 += c0 * bf2f(r0.w);
        a0 += c1 * bf2f(r1.x); a1 += c1 * bf2f(r1.y); a2 += c1 * bf2f(r1.z); a3 += c1 * bf2f(r1.w);
        a0 += c2 * bf2f(r2.x); a1 += c2 * bf2f(r2.y); a2 += c2 * bf2f(r2.z); a3 += c2 * bf2f(r2.w);
        a0 += c3 * bf2f(r3.x); a1 += c3 * bf2f(r3.y); a2 += c3 * bf2f(r3.z); a3 += c3 * bf2f(r3.w);
        den += c0 + c1 + c2 + c3;
    }
    for (; i < end; ++i) {
        int e = eid[i];
        int d = dst[e];
        float c = coef[(size_t)e * 4 + head];
        ushort4 r = *(const ushort4*)(S1 + (size_t)d * HF + lane * 4);
        a0 += c * bf2f(r.x); a1 += c * bf2f(r.y); a2 += c * bf2f(r.z); a3 += c * bf2f(r.w);
        den += c;
    }
    float4 b = *(const float4*)(bias + lane * 4);
    float v0 = a0 / den + b.x;
    float v1 = a1 / den + b.y;
    float v2 = a2 / den + b.z;
    float v3 = a3 / den + b.w;
    v0 = v0 > 0.f ? v0 : expm1f(v0);
    v1 = v1 > 0.f ? v1 : expm1f(v1);
    v2 = v2 > 0.f ? v2 : expm1f(v2);
    v3 = v3 > 0.f ? v3 : expm1f(v3);
    ushort4 o;
    o.x = f2bf(v0); o.y = f2bf(v1); o.z = f2bf(v2); o.w = f2bf(v3);
    *(ushort4*)(hcat + (size_t)n * HF + lane * 4) = o;
}

// --------------------------- gather + normalize + bias, classifier (wave/node)
__global__ __launch_bounds__(256) void gather2_kernel(const int* __restrict__ starts,
                                                      const int* __restrict__ eid,
                                                      const int* __restrict__ dst,
                                                      const float* __restrict__ coef,
                                                      const ushort* __restrict__ S2,
                                                      const float* __restrict__ bias,
                                                      float* __restrict__ out, int N) {
    int n = (int)((blockIdx.x * blockDim.x + threadIdx.x) >> 6);
    int lane = threadIdx.x & 63;
    if (n >= N) return;
    int beg = starts[n], end = starts[n + 1];
    float acc = 0.f, den = 0.f;
    int i = beg;
    for (; i + 4 <= end; i += 4) {
        int e0 = eid[i], e1 = eid[i + 1], e2 = eid[i + 2], e3 = eid[i + 3];
        int d0 = dst[e0], d1 = dst[e1], d2 = dst[e2], d3 = dst[e3];
        float c0 = coef[e0], c1 = coef[e1], c2 = coef[e2], c3 = coef[e3];
        ushort r0 = S2[(size_t)d0 * OUT_DIM + lane];
        ushort r1 = S2[(size_t)d1 * OUT_DIM + lane];
        ushort r2 = S2[(size_t)d2 * OUT_DIM + lane];
        ushort r3 = S2[(size_t)d3 * OUT_DIM + lane];
        acc += c0 * bf2f(r0) + c1 * bf2f(r1) + c2 * bf2f(r2) + c3 * bf2f(r3);
        den += c0 + c1 + c2 + c3;
    }
    for (; i < end; ++i) {
        int e = eid[i];
        int d = dst[e];
        float c = coef[e];
        acc += c * bf2f(S2[(size_t)d * OUT_DIM + lane]);
        den += c;
    }
    out[(size_t)n * OUT_DIM + lane] = acc / den + bias[lane];
}

// ===========================================================================
extern "C" void kernel_launch(void* const* d_in, const int* in_sizes, int n_in,
                              void* d_out, int out_size, void* d_ws, size_t ws_size,
                              hipStream_t stream) {
    const float* x      = (const float*)d_in[0];
    const int*   edges  = (const int*)d_in[1];
    const float* Wlin_h = (const float*)d_in[2];
    const float* Wseq_h = (const float*)d_in[3];
    const float* a1_h   = (const float*)d_in[4];
    const float* b1_h   = (const float*)d_in[5];
    const float* a2_h   = (const float*)d_in[6];
    const float* b2_h   = (const float*)d_in[7];
    const float* bias_h = (const float*)d_in[8];
    const float* Wlin_c = (const float*)d_in[9];
    const float* Wseq_c = (const float*)d_in[10];
    const float* a1_c   = (const float*)d_in[11];
    const float* b1_c   = (const float*)d_in[12];
    const float* a2_c   = (const float*)d_in[13];
    const float* b2_c   = (const float*)d_in[14];
    const float* bias_c = (const float*)d_in[15];

    const int N = in_sizes[0] / IN_DIM;
    const int E = in_sizes[1] / 2;
    const int* src = edges;
    const int* dst = edges + E;

    char* ws = (char*)d_ws;
    size_t off = 0;
    ushort* XB    = (ushort*)(ws + off); off += (size_t)N * IN_DIM * 2;
    ushort* WC1   = (ushort*)(ws + off); off += (size_t)HF * IN_DIM * 2;
    ushort* WC2   = (ushort*)(ws + off); off += (size_t)OUT_DIM * HF * 2;
    ushort* S1    = (ushort*)(ws + off); off += (size_t)N * HF * 2;
    ushort* S2    = S1;  // S1 dead after gather1; reuse for S2 [N][64]
    ushort* HCAT  = (ushort*)(ws + off); off += (size_t)N * HF * 2;
    float*  COEF1 = (float*)(ws + off);  off += (size_t)E * 4 * 4;
    float*  COEF2 = COEF1;
    float*  F1    = (float*)(ws + off);  off += (size_t)N * H_NUM * 4;
    float*  F2    = (float*)(ws + off);  off += (size_t)N * H_NUM * 4;
    float*  F1c   = (float*)(ws + off);  off += (size_t)N * 4;
    float*  F2c   = (float*)(ws + off);  off += (size_t)N * 4;
    int* COUNTS   = (int*)(ws + off);    off += (size_t)N * 4;
    int* STARTS   = (int*)(ws + off);    off += ((size_t)N + 1) * 4;
    int* CURSOR   = (int*)(ws + off);    off += (size_t)N * 4;
    int* EID      = (int*)(ws + off);    off += (size_t)E * 4;
    int* LEXCL    = (int*)(ws + off);    off += (size_t)N * 4;
    int* PART     = (int*)(ws + off);    off += 512 * 4;

    float* out = (float*)d_out;

    const int eg = (E + 255) / 256;
    const int NB = (N + 255) / 256;

    // ---- CSR build (shared by both layers)
    hipLaunchKernelGGL(zero_i32, dim3(NB), dim3(256), 0, stream, COUNTS, N);
    hipLaunchKernelGGL(hist_kernel, dim3(eg), dim3(256), 0, stream, src, COUNTS, E);
    hipLaunchKernelGGL(scan_blk, dim3(NB), dim3(256), 0, stream, COUNTS, LEXCL, PART, N);
    hipLaunchKernelGGL(scan_part, dim3(1), dim3(256), 0, stream, PART, NB);
    hipLaunchKernelGGL(scan_add, dim3(NB), dim3(256), 0, stream, LEXCL, PART, STARTS, CURSOR, N, NB);
    hipLaunchKernelGGL(scatter_kernel, dim3(eg), dim3(256), 0, stream, src, CURSOR, EID, E);

    // ---- convert x to bf16; fold weights (bf16 out)
    hipLaunchKernelGGL(f2bf_kernel, dim3((N * IN_DIM / 8 + 255) / 256), dim3(256), 0, stream,
                       x, XB, N * IN_DIM / 8);
    hipLaunchKernelGGL(wcomb1_kernel, dim3((HF * IN_DIM + 255) / 256), dim3(256),
                       0, stream, Wlin_h, Wseq_h, WC1);
    hipLaunchKernelGGL(wcomb2_kernel, dim3((OUT_DIM * HF + 255) / 256), dim3(256),
                       0, stream, Wlin_c, Wseq_c, WC2);

    // ---- layer 1: S1 = x @ Wc1^T
    hipLaunchKernelGGL((gemm_bf16<128, IN_DIM>), dim3((N + 127) / 128, HF / 128), dim3(256),
                       0, stream, XB, WC1, S1, N, HF);

    // ---- f1/f2 per (node, head), per-edge coefs
    hipLaunchKernelGGL(fvec_h_kernel, dim3((N * H_NUM + 3) / 4), dim3(256), 0, stream,
                       S1, a1_h, b1_h, a2_h, b2_h, F1, F2, N * H_NUM);
    hipLaunchKernelGGL(coef1_kernel, dim3(eg), dim3(256), 0, stream,
                       src, dst, F1, F2, (float4*)COEF1, E);

    // ---- gather layer 1 (fused normalize + bias + ELU) -> HCAT bf16
    hipLaunchKernelGGL(gather1_kernel, dim3((N + 3) / 4), dim3(256), 0, stream,
                       STARTS, EID, dst, COEF1, S1, bias_h, HCAT, N);

    // ---- classifier: S2 = hcat @ Wc2^T
    hipLaunchKernelGGL((gemm_bf16<64, HF>), dim3((N + 127) / 128, 1), dim3(256),
                       0, stream, HCAT, WC2, S2, N, OUT_DIM);

    // ---- f1/f2 classifier, per-edge coefs
    hipLaunchKernelGGL(fvec_c_kernel, dim3((N + 3) / 4), dim3(256), 0, stream,
                       S2, a1_c, b1_c, a2_c, b2_c, F1c, F2c, N);
    hipLaunchKernelGGL(coef2_kernel, dim3(eg), dim3(256), 0, stream,
                       src, dst, F1c, F2c, COEF2, E);

    // ---- gather classifier (fused normalize + bias) -> out fp32
    hipLaunchKernelGGL(gather2_kernel, dim3((N + 3) / 4), dim3(256), 0, stream,
                       STARTS, EID, dst, COEF2, S2, bias_c, out, N);
}

// Round 5
// 307.123 us; speedup vs baseline: 4.3999x; 1.1822x over previous
//
#include <hip/hip_runtime.h>
#include <hip/hip_bf16.h>
#include <cstddef>
#include <cstdint>

#define IN_DIM 512
#define R_DIM 128
#define F_DIM 64
#define H_NUM 4
#define OUT_DIM 64
#define HF 256  // H_NUM * F_DIM

typedef __attribute__((ext_vector_type(4))) float f32x4;
typedef __attribute__((ext_vector_type(8))) short bf16x8;

typedef const __attribute__((address_space(1))) void gas_void;
typedef __attribute__((address_space(3))) void las_void;

__device__ __forceinline__ float bf2f(ushort u) {
    union { uint i; float f; } v; v.i = ((uint)u) << 16; return v.f;
}
__device__ __forceinline__ ushort f2bf(float f) {
    union { float f; uint i; } v; v.f = f;
    uint r = v.i + 0x7fff + ((v.i >> 16) & 1);
    return (ushort)(r >> 16);
}

// ---------------------------------------------------------------- zero ints
__global__ __launch_bounds__(256) void zero_i32(int* __restrict__ p, int n) {
    int i = blockIdx.x * 256 + threadIdx.x;
    if (i < n) p[i] = 0;
}

// ------------------------------------------------- fold W_seq @ W_lin (heads)
__global__ __launch_bounds__(256) void wcomb1_kernel(const float* __restrict__ Wlin,
                                                     const float* __restrict__ Wseq,
                                                     ushort* __restrict__ Wc) {
    int idx = blockIdx.x * 256 + threadIdx.x;
    if (idx >= H_NUM * F_DIM * IN_DIM) return;
    int i  = idx & (IN_DIM - 1);
    int hf = idx >> 9;          // h*64 + f
    int h  = hf >> 6;
    const float* ws = Wseq + (size_t)hf * R_DIM;
    const float* wl = Wlin + (size_t)h * R_DIM * IN_DIM + i;
    float acc = 0.0f;
#pragma unroll 8
    for (int r = 0; r < R_DIM; ++r) acc += ws[r] * wl[(size_t)r * IN_DIM];
    Wc[idx] = f2bf(acc);
}

// ---------------------------------------------- fold W_seq_c @ W_lin_c (clf)
__global__ __launch_bounds__(256) void wcomb2_kernel(const float* __restrict__ Wlin,
                                                     const float* __restrict__ Wseq,
                                                     ushort* __restrict__ Wc) {
    int idx = blockIdx.x * 256 + threadIdx.x;
    if (idx >= OUT_DIM * HF) return;
    int j = idx & (HF - 1);
    int o = idx >> 8;
    const float* ws = Wseq + (size_t)o * R_DIM;
    const float* wl = Wlin + j;
    float acc = 0.0f;
#pragma unroll 8
    for (int r = 0; r < R_DIM; ++r) acc += ws[r] * wl[(size_t)r * HF];
    Wc[idx] = f2bf(acc);
}

// ----------------------------- bf16 MFMA GEMM TN, fp32 A converted in-flight
// C[m][n] = sum_k A[m][k]*B[n][k]; A [M][K] fp32, B [Ntot][K] bf16, C bf16.
// BM=128, BK=64, 256 threads. A: reg-staged (f32->bf16 cvt + swizzled ds_write);
// B: global_load_lds with pre-swizzled source.
template<int BN, int K>
__global__ __launch_bounds__(256) void gemm_f32a(const float* __restrict__ A,
                                                 const ushort* __restrict__ B,
                                                 ushort* __restrict__ C,
                                                 int M, int Ntot) {
    constexpr int NF = BN / 16;
    __shared__ ushort As[128 * 64];
    __shared__ ushort Bs[BN * 64];
    const int tid = threadIdx.x;
    const int wave = tid >> 6;
    const int lane = tid & 63;
    const int lr = lane & 15;
    const int lg = lane >> 4;
    const int m0 = blockIdx.x * 128;
    const int n0 = blockIdx.y * BN;

    int aoff[2][2], boff[NF][2];
#pragma unroll
    for (int rb = 0; rb < 2; ++rb)
#pragma unroll
        for (int ks = 0; ks < 2; ++ks) {
            int row = wave * 32 + rb * 16 + lr;
            int c = ks * 4 + lg;
            aoff[rb][ks] = row * 128 + ((c ^ (row & 7)) * 16);
        }
#pragma unroll
    for (int cb = 0; cb < NF; ++cb)
#pragma unroll
        for (int ks = 0; ks < 2; ++ks) {
            int row = cb * 16 + lr;
            int c = ks * 4 + lg;
            boff[cb][ks] = row * 128 + ((c ^ (row & 7)) * 16);
        }

    // A staging geometry (constant per thread): 4 rounds x 256 thr x 16B bf16
    int s_row[4], s_ldsoff[4];
#pragma unroll
    for (int r = 0; r < 4; ++r) {
        int off = r * 4096 + tid * 16;
        int row = off >> 7;
        int chunk = (off >> 4) & 7;
        s_row[r] = row;
        s_ldsoff[r] = row * 128 + ((chunk ^ (row & 7)) * 16);
    }

    f32x4 acc[2][NF];
#pragma unroll
    for (int rb = 0; rb < 2; ++rb)
#pragma unroll
        for (int cb = 0; cb < NF; ++cb) acc[rb][cb] = (f32x4)0.0f;

    for (int k0 = 0; k0 < K; k0 += 64) {
        // ---- stage B via global_load_lds (pre-swizzled source)
#pragma unroll
        for (int r = 0; r < BN / 32; ++r) {
            int off = r * 4096 + tid * 16;
            int row = off >> 7;
            int kch = ((off >> 4) & 7) ^ (row & 7);
            const ushort* g = B + (size_t)(n0 + row) * K + k0 + kch * 8;
            __builtin_amdgcn_global_load_lds((gas_void*)g,
                                             (las_void*)((char*)Bs + off), 16, 0, 0);
        }
        // ---- stage A: fp32 load -> bf16 cvt -> swizzled ds_write
#pragma unroll
        for (int r = 0; r < 4; ++r) {
            int row = s_row[r];
            int grow = m0 + row;
            if (grow >= M) grow = M - 1;   // clamp (OOB rows never stored)
            int chunk = (s_ldsoff[r] >> 4) & 7;  // unswizzled k-chunk recovered below
            // NOTE: global side must read the *logical* chunk for this lds slot:
            // lds slot holds chunk c_sw = chunk^(row&7) applied at write; we instead
            // read logical chunk = ((r*4096+tid*16)>>4)&7 and write to swizzled slot.
            int lchunk = (((r * 4096 + tid * 16) >> 4) & 7);
            const float* g = A + (size_t)grow * K + k0 + lchunk * 8;
            float4 v0 = *(const float4*)(g);
            float4 v1 = *(const float4*)(g + 4);
            ushort us[8] = {f2bf(v0.x), f2bf(v0.y), f2bf(v0.z), f2bf(v0.w),
                            f2bf(v1.x), f2bf(v1.y), f2bf(v1.z), f2bf(v1.w)};
            int ldsoff = row * 128 + ((lchunk ^ (row & 7)) * 16);
            *(uint4*)((char*)As + ldsoff) = *(const uint4*)us;
        }
        __syncthreads();
#pragma unroll
        for (int ks = 0; ks < 2; ++ks) {
            bf16x8 af[2], bfr[NF];
#pragma unroll
            for (int rb = 0; rb < 2; ++rb)
                af[rb] = *(const bf16x8*)((const char*)As + aoff[rb][ks]);
#pragma unroll
            for (int cb = 0; cb < NF; ++cb)
                bfr[cb] = *(const bf16x8*)((const char*)Bs + boff[cb][ks]);
#pragma unroll
            for (int rb = 0; rb < 2; ++rb)
#pragma unroll
                for (int cb = 0; cb < NF; ++cb)
                    acc[rb][cb] = __builtin_amdgcn_mfma_f32_16x16x32_bf16(
                        af[rb], bfr[cb], acc[rb][cb], 0, 0, 0);
        }
        __syncthreads();
    }

#pragma unroll
    for (int rb = 0; rb < 2; ++rb) {
        int rowb = m0 + wave * 32 + rb * 16 + lg * 4;
#pragma unroll
        for (int cb = 0; cb < NF; ++cb) {
            int col = n0 + cb * 16 + lr;
#pragma unroll
            for (int r = 0; r < 4; ++r) {
                int row = rowb + r;
                if (row < M) C[(size_t)row * Ntot + col] = f2bf(acc[rb][cb][r]);
            }
        }
    }
}

// --------------------------------------------------------- bf16 MFMA GEMM TN
template<int BN, int K>
__global__ __launch_bounds__(256) void gemm_bf16(const ushort* __restrict__ A,
                                                 const ushort* __restrict__ B,
                                                 ushort* __restrict__ C,
                                                 int M, int Ntot) {
    constexpr int NF = BN / 16;
    __shared__ ushort As[128 * 64];
    __shared__ ushort Bs[BN * 64];
    const int tid = threadIdx.x;
    const int wave = tid >> 6;
    const int lane = tid & 63;
    const int lr = lane & 15;
    const int lg = lane >> 4;
    const int m0 = blockIdx.x * 128;
    const int n0 = blockIdx.y * BN;

    int aoff[2][2], boff[NF][2];
#pragma unroll
    for (int rb = 0; rb < 2; ++rb)
#pragma unroll
        for (int ks = 0; ks < 2; ++ks) {
            int row = wave * 32 + rb * 16 + lr;
            int c = ks * 4 + lg;
            aoff[rb][ks] = row * 128 + ((c ^ (row & 7)) * 16);
        }
#pragma unroll
    for (int cb = 0; cb < NF; ++cb)
#pragma unroll
        for (int ks = 0; ks < 2; ++ks) {
            int row = cb * 16 + lr;
            int c = ks * 4 + lg;
            boff[cb][ks] = row * 128 + ((c ^ (row & 7)) * 16);
        }

    f32x4 acc[2][NF];
#pragma unroll
    for (int rb = 0; rb < 2; ++rb)
#pragma unroll
        for (int cb = 0; cb < NF; ++cb) acc[rb][cb] = (f32x4)0.0f;

    for (int k0 = 0; k0 < K; k0 += 64) {
#pragma unroll
        for (int r = 0; r < 4; ++r) {
            int off = r * 4096 + tid * 16;
            int row = off >> 7;
            int kch = ((off >> 4) & 7) ^ (row & 7);
            const ushort* g = A + (size_t)(m0 + row) * K + k0 + kch * 8;
            __builtin_amdgcn_global_load_lds((gas_void*)g,
                                             (las_void*)((char*)As + off), 16, 0, 0);
        }
#pragma unroll
        for (int r = 0; r < BN / 32; ++r) {
            int off = r * 4096 + tid * 16;
            int row = off >> 7;
            int kch = ((off >> 4) & 7) ^ (row & 7);
            const ushort* g = B + (size_t)(n0 + row) * K + k0 + kch * 8;
            __builtin_amdgcn_global_load_lds((gas_void*)g,
                                             (las_void*)((char*)Bs + off), 16, 0, 0);
        }
        __syncthreads();
#pragma unroll
        for (int ks = 0; ks < 2; ++ks) {
            bf16x8 af[2], bfr[NF];
#pragma unroll
            for (int rb = 0; rb < 2; ++rb)
                af[rb] = *(const bf16x8*)((const char*)As + aoff[rb][ks]);
#pragma unroll
            for (int cb = 0; cb < NF; ++cb)
                bfr[cb] = *(const bf16x8*)((const char*)Bs + boff[cb][ks]);
#pragma unroll
            for (int rb = 0; rb < 2; ++rb)
#pragma unroll
                for (int cb = 0; cb < NF; ++cb)
                    acc[rb][cb] = __builtin_amdgcn_mfma_f32_16x16x32_bf16(
                        af[rb], bfr[cb], acc[rb][cb], 0, 0, 0);
        }
        __syncthreads();
    }

#pragma unroll
    for (int rb = 0; rb < 2; ++rb) {
        int rowb = m0 + wave * 32 + rb * 16 + lg * 4;
#pragma unroll
        for (int cb = 0; cb < NF; ++cb) {
            int col = n0 + cb * 16 + lr;
#pragma unroll
            for (int r = 0; r < 4; ++r) {
                int row = rowb + r;
                if (row < M) C[(size_t)row * Ntot + col] = f2bf(acc[rb][cb][r]);
            }
        }
    }
}

// ------------------------------------------- f1/f2 dots, heads layer (wave/nh)
__global__ __launch_bounds__(256) void fvec_h_kernel(const ushort* __restrict__ S,
                                                     const float* __restrict__ a1,
                                                     const float* __restrict__ b1,
                                                     const float* __restrict__ a2,
                                                     const float* __restrict__ b2,
                                                     float* __restrict__ f1,
                                                     float* __restrict__ f2,
                                                     int NH) {
    int w = (int)((blockIdx.x * blockDim.x + threadIdx.x) >> 6);
    int lane = threadIdx.x & 63;
    if (w >= NH) return;
    int n = w >> 2;
    int h = w & 3;
    float s = bf2f(S[(size_t)n * HF + h * 64 + lane]);
    float p1 = s * a1[h * 64 + lane];
    float p2 = s * a2[h * 64 + lane];
#pragma unroll
    for (int off = 32; off > 0; off >>= 1) {
        p1 += __shfl_down(p1, off, 64);
        p2 += __shfl_down(p2, off, 64);
    }
    if (lane == 0) {
        f1[w] = p1 + b1[h];
        f2[w] = p2 + b2[h];
    }
}

// ------------------------------------------- f1/f2 dots, classifier (wave/n)
__global__ __launch_bounds__(256) void fvec_c_kernel(const ushort* __restrict__ S,
                                                     const float* __restrict__ a1,
                                                     const float* __restrict__ b1,
                                                     const float* __restrict__ a2,
                                                     const float* __restrict__ b2,
                                                     float* __restrict__ f1,
                                                     float* __restrict__ f2,
                                                     int N) {
    int w = (int)((blockIdx.x * blockDim.x + threadIdx.x) >> 6);
    int lane = threadIdx.x & 63;
    if (w >= N) return;
    float s = bf2f(S[(size_t)w * OUT_DIM + lane]);
    float p1 = s * a1[lane];
    float p2 = s * a2[lane];
#pragma unroll
    for (int off = 32; off > 0; off >>= 1) {
        p1 += __shfl_down(p1, off, 64);
        p2 += __shfl_down(p2, off, 64);
    }
    if (lane == 0) {
        f1[w] = p1 + b1[0];
        f2[w] = p2 + b2[0];
    }
}

// ------------------------------------------------------------ CSR: histogram
__global__ __launch_bounds__(256) void hist_kernel(const int* __restrict__ src,
                                                   int* __restrict__ counts, int E) {
    int e = blockIdx.x * 256 + threadIdx.x;
    if (e < E) atomicAdd(&counts[src[e]], 1);
}

// ----------------------------------------- scan stage 1: per-block excl scan
__global__ __launch_bounds__(256) void scan_blk(const int* __restrict__ counts,
                                                int* __restrict__ lexcl,
                                                int* __restrict__ part, int N) {
    __shared__ int wsum[4];
    int t = threadIdx.x;
    int g = blockIdx.x * 256 + t;
    int lane = t & 63, wid = t >> 6;
    int v = (g < N) ? counts[g] : 0;
    int x = v;
#pragma unroll
    for (int off = 1; off < 64; off <<= 1) {
        int u = __shfl_up(x, off, 64);
        if (lane >= off) x += u;
    }
    if (lane == 63) wsum[wid] = x;
    __syncthreads();
    int woff = 0;
#pragma unroll
    for (int w = 0; w < 3; ++w) if (w < wid) woff += wsum[w];
    int incl = x + woff;
    if (g < N) lexcl[g] = incl - v;
    if (t == 255) part[blockIdx.x] = incl;
}

// --------------------------------- scan stage 2: excl scan of block partials
__global__ __launch_bounds__(256) void scan_part(int* __restrict__ part, int nb) {
    __shared__ int wsum[4];
    int t = threadIdx.x;
    int lane = t & 63, wid = t >> 6;
    int v = (t < nb) ? part[t] : 0;
    int x = v;
#pragma unroll
    for (int off = 1; off < 64; off <<= 1) {
        int u = __shfl_up(x, off, 64);
        if (lane >= off) x += u;
    }
    if (lane == 63) wsum[wid] = x;
    __syncthreads();
    int woff = 0;
#pragma unroll
    for (int w = 0; w < 3; ++w) if (w < wid) woff += wsum[w];
    int incl = x + woff;
    __syncthreads();
    if (t < nb) part[t] = incl - v;
    if (t == 255) part[nb] = incl;   // grand total
}

// ------------------------------------- scan stage 3: add offsets, emit CSR ptrs
__global__ __launch_bounds__(256) void scan_add(const int* __restrict__ lexcl,
                                                const int* __restrict__ part,
                                                int* __restrict__ starts,
                                                int* __restrict__ cursor, int N, int nb) {
    int g = blockIdx.x * 256 + threadIdx.x;
    if (g < N) {
        int s = lexcl[g] + part[blockIdx.x];
        starts[g] = s;
        cursor[g] = s;
    }
    if (g == 0) starts[N] = part[nb];
}

// ------------------------- CSR: position scatter (writes sorted dst directly)
__global__ __launch_bounds__(256) void scatter_kernel(const int* __restrict__ src,
                                                      const int* __restrict__ dst,
                                                      int* __restrict__ cursor,
                                                      int* __restrict__ dsts, int E) {
    int e = blockIdx.x * 256 + threadIdx.x;
    if (e >= E) return;
    int p = atomicAdd(&cursor[src[e]], 1);
    dsts[p] = dst[e];
}

// ----------------------- gather + normalize + bias + ELU, heads (wave/node)
// lane owns features lane*4..+3 (head = lane>>4). coef computed inline:
// f1[n] wave-uniform, f2[d] wave-uniform 16B load (800KB, L2-resident).
__global__ __launch_bounds__(256) void gather1_kernel(const int* __restrict__ starts,
                                                      const int* __restrict__ dsts,
                                                      const float* __restrict__ f1,
                                                      const float* __restrict__ f2,
                                                      const ushort* __restrict__ S1,
                                                      const float* __restrict__ bias,
                                                      ushort* __restrict__ hcat, int N) {
    int n = (int)((blockIdx.x * blockDim.x + threadIdx.x) >> 6);
    int lane = threadIdx.x & 63;
    if (n >= N) return;
    const int head = lane >> 4;
    const float f1h = f1[(size_t)n * 4 + head];   // uniform per 16-lane group
    int beg = starts[n], end = starts[n + 1];
    float a0 = 0.f, a1 = 0.f, a2 = 0.f, a3 = 0.f, den = 0.f;
    int i = beg;
    for (; i + 4 <= end; i += 4) {
        int4 d4 = *(const int4*)(dsts + i);
        float g0 = f2[(size_t)d4.x * 4 + head];
        float g1 = f2[(size_t)d4.y * 4 + head];
        float g2 = f2[(size_t)d4.z * 4 + head];
        float g3 = f2[(size_t)d4.w * 4 + head];
        ushort4 r0 = *(const ushort4*)(S1 + (size_t)d4.x * HF + lane * 4);
        ushort4 r1 = *(const ushort4*)(S1 + (size_t)d4.y * HF + lane * 4);
        ushort4 r2 = *(const ushort4*)(S1 + (size_t)d4.z * HF + lane * 4);
        ushort4 r3 = *(const ushort4*)(S1 + (size_t)d4.w * HF + lane * 4);
        float l0 = f1h + g0; l0 = l0 > 0.f ? l0 : 0.2f * l0;
        float l1 = f1h + g1; l1 = l1 > 0.f ? l1 : 0.2f * l1;
        float l2 = f1h + g2; l2 = l2 > 0.f ? l2 : 0.2f * l2;
        float l3 = f1h + g3; l3 = l3 > 0.f ? l3 : 0.2f * l3;
        float c0 = expf(l0), c1 = expf(l1), c2 = expf(l2), c3 = expf(l3);
        a0 += c0 * bf2f(r0.x); a1 += c0 * bf2f(r0.y); a2 += c0 * bf2f(r0.z); a3 += c0 * bf2f(r0.w);
        a0 += c1 * bf2f(r1.x); a1 += c1 * bf2f(r1.y); a2 += c1 * bf2f(r1.z); a3 += c1 * bf2f(r1.w);
        a0 += c2 * bf2f(r2.x); a1 += c2 * bf2f(r2.y); a2 += c2 * bf2f(r2.z); a3 += c2 * bf2f(r2.w);
        a0 += c3 * bf2f(r3.x); a1 += c3 * bf2f(r3.y); a2 += c3 * bf2f(r3.z); a3 += c3 * bf2f(r3.w);
        den += c0 + c1 + c2 + c3;
    }
    for (; i < end; ++i) {
        int d = dsts[i];
        float g = f2[(size_t)d * 4 + head];
        ushort4 r = *(const ushort4*)(S1 + (size_t)d * HF + lane * 4);
        float l = f1h + g; l = l > 0.f ? l : 0.2f * l;
        float c = expf(l);
        a0 += c * bf2f(r.x); a1 += c * bf2f(r.y); a2 += c * bf2f(r.z); a3 += c * bf2f(r.w);
        den += c;
    }
    float4 b = *(const float4*)(bias + lane * 4);
    float v0 = a0 / den + b.x;
    float v1 = a1 / den + b.y;
    float v2 = a2 / den + b.z;
    float v3 = a3 / den + b.w;
    v0 = v0 > 0.f ? v0 : expm1f(v0);
    v1 = v1 > 0.f ? v1 : expm1f(v1);
    v2 = v2 > 0.f ? v2 : expm1f(v2);
    v3 = v3 > 0.f ? v3 : expm1f(v3);
    ushort4 o;
    o.x = f2bf(v0); o.y = f2bf(v1); o.z = f2bf(v2); o.w = f2bf(v3);
    *(ushort4*)(hcat + (size_t)n * HF + lane * 4) = o;
}

// --------------------------- gather + normalize + bias, classifier (wave/node)
__global__ __launch_bounds__(256) void gather2_kernel(const int* __restrict__ starts,
                                                      const int* __restrict__ dsts,
                                                      const float* __restrict__ f1,
                                                      const float* __restrict__ f2,
                                                      const ushort* __restrict__ S2,
                                                      const float* __restrict__ bias,
                                                      float* __restrict__ out, int N) {
    int n = (int)((blockIdx.x * blockDim.x + threadIdx.x) >> 6);
    int lane = threadIdx.x & 63;
    if (n >= N) return;
    const float f1u = f1[n];
    int beg = starts[n], end = starts[n + 1];
    float acc = 0.f, den = 0.f;
    int i = beg;
    for (; i + 4 <= end; i += 4) {
        int4 d4 = *(const int4*)(dsts + i);
        float g0 = f2[d4.x], g1 = f2[d4.y], g2 = f2[d4.z], g3 = f2[d4.w];
        ushort r0 = S2[(size_t)d4.x * OUT_DIM + lane];
        ushort r1 = S2[(size_t)d4.y * OUT_DIM + lane];
        ushort r2 = S2[(size_t)d4.z * OUT_DIM + lane];
        ushort r3 = S2[(size_t)d4.w * OUT_DIM + lane];
        float l0 = f1u + g0; l0 = l0 > 0.f ? l0 : 0.2f * l0;
        float l1 = f1u + g1; l1 = l1 > 0.f ? l1 : 0.2f * l1;
        float l2 = f1u + g2; l2 = l2 > 0.f ? l2 : 0.2f * l2;
        float l3 = f1u + g3; l3 = l3 > 0.f ? l3 : 0.2f * l3;
        float c0 = expf(l0), c1 = expf(l1), c2 = expf(l2), c3 = expf(l3);
        acc += c0 * bf2f(r0) + c1 * bf2f(r1) + c2 * bf2f(r2) + c3 * bf2f(r3);
        den += c0 + c1 + c2 + c3;
    }
    for (; i < end; ++i) {
        int d = dsts[i];
        float l = f1u + f2[d]; l = l > 0.f ? l : 0.2f * l;
        float c = expf(l);
        acc += c * bf2f(S2[(size_t)d * OUT_DIM + lane]);
        den += c;
    }
    out[(size_t)n * OUT_DIM + lane] = acc / den + bias[lane];
}

// ===========================================================================
extern "C" void kernel_launch(void* const* d_in, const int* in_sizes, int n_in,
                              void* d_out, int out_size, void* d_ws, size_t ws_size,
                              hipStream_t stream) {
    const float* x      = (const float*)d_in[0];
    const int*   edges  = (const int*)d_in[1];
    const float* Wlin_h = (const float*)d_in[2];
    const float* Wseq_h = (const float*)d_in[3];
    const float* a1_h   = (const float*)d_in[4];
    const float* b1_h   = (const float*)d_in[5];
    const float* a2_h   = (const float*)d_in[6];
    const float* b2_h   = (const float*)d_in[7];
    const float* bias_h = (const float*)d_in[8];
    const float* Wlin_c = (const float*)d_in[9];
    const float* Wseq_c = (const float*)d_in[10];
    const float* a1_c   = (const float*)d_in[11];
    const float* b1_c   = (const float*)d_in[12];
    const float* a2_c   = (const float*)d_in[13];
    const float* b2_c   = (const float*)d_in[14];
    const float* bias_c = (const float*)d_in[15];

    const int N = in_sizes[0] / IN_DIM;
    const int E = in_sizes[1] / 2;
    const int* src = edges;
    const int* dst = edges + E;

    char* ws = (char*)d_ws;
    size_t off = 0;
    ushort* WC1   = (ushort*)(ws + off); off += (size_t)HF * IN_DIM * 2;
    ushort* WC2   = (ushort*)(ws + off); off += (size_t)OUT_DIM * HF * 2;
    ushort* S1    = (ushort*)(ws + off); off += (size_t)N * HF * 2;
    ushort* S2    = S1;  // S1 dead after gather1; reuse for S2 [N][64]
    ushort* HCAT  = (ushort*)(ws + off); off += (size_t)N * HF * 2;
    float*  F1    = (float*)(ws + off);  off += (size_t)N * H_NUM * 4;
    float*  F2    = (float*)(ws + off);  off += (size_t)N * H_NUM * 4;
    float*  F1c   = (float*)(ws + off);  off += (size_t)N * 4;
    float*  F2c   = (float*)(ws + off);  off += (size_t)N * 4;
    int* COUNTS   = (int*)(ws + off);    off += (size_t)N * 4;
    int* STARTS   = (int*)(ws + off);    off += ((size_t)N + 1) * 4;
    int* CURSOR   = (int*)(ws + off);    off += (size_t)N * 4;
    int* DSTS     = (int*)(ws + off);    off += (size_t)E * 4;
    int* LEXCL    = (int*)(ws + off);    off += (size_t)N * 4;
    int* PART     = (int*)(ws + off);    off += 512 * 4;

    float* out = (float*)d_out;

    const int eg = (E + 255) / 256;
    const int NB = (N + 255) / 256;

    // ---- CSR build (shared by both layers); DSTS = dst sorted by src
    hipLaunchKernelGGL(zero_i32, dim3(NB), dim3(256), 0, stream, COUNTS, N);
    hipLaunchKernelGGL(hist_kernel, dim3(eg), dim3(256), 0, stream, src, COUNTS, E);
    hipLaunchKernelGGL(scan_blk, dim3(NB), dim3(256), 0, stream, COUNTS, LEXCL, PART, N);
    hipLaunchKernelGGL(scan_part, dim3(1), dim3(256), 0, stream, PART, NB);
    hipLaunchKernelGGL(scan_add, dim3(NB), dim3(256), 0, stream, LEXCL, PART, STARTS, CURSOR, N, NB);
    hipLaunchKernelGGL(scatter_kernel, dim3(eg), dim3(256), 0, stream, src, dst, CURSOR, DSTS, E);

    // ---- fold weights (bf16 out)
    hipLaunchKernelGGL(wcomb1_kernel, dim3((HF * IN_DIM + 255) / 256), dim3(256),
                       0, stream, Wlin_h, Wseq_h, WC1);
    hipLaunchKernelGGL(wcomb2_kernel, dim3((OUT_DIM * HF + 255) / 256), dim3(256),
                       0, stream, Wlin_c, Wseq_c, WC2);

    // ---- layer 1: S1 = x @ Wc1^T  (fp32 A converted in-flight)
    hipLaunchKernelGGL((gemm_f32a<128, IN_DIM>), dim3((N + 127) / 128, HF / 128), dim3(256),
                       0, stream, x, WC1, S1, N, HF);

    // ---- f1/f2 per (node, head)
    hipLaunchKernelGGL(fvec_h_kernel, dim3((N * H_NUM + 3) / 4), dim3(256), 0, stream,
                       S1, a1_h, b1_h, a2_h, b2_h, F1, F2, N * H_NUM);

    // ---- gather layer 1 (inline coef + normalize + bias + ELU) -> HCAT bf16
    hipLaunchKernelGGL(gather1_kernel, dim3((N + 3) / 4), dim3(256), 0, stream,
                       STARTS, DSTS, F1, F2, S1, bias_h, HCAT, N);

    // ---- classifier: S2 = hcat @ Wc2^T
    hipLaunchKernelGGL((gemm_bf16<64, HF>), dim3((N + 127) / 128, 1), dim3(256),
                       0, stream, HCAT, WC2, S2, N, OUT_DIM);

    // ---- f1/f2 classifier
    hipLaunchKernelGGL(fvec_c_kernel, dim3((N + 3) / 4), dim3(256), 0, stream,
                       S2, a1_c, b1_c, a2_c, b2_c, F1c, F2c, N);

    // ---- gather classifier (inline coef + normalize + bias) -> out fp32
    hipLaunchKernelGGL(gather2_kernel, dim3((N + 3) / 4), dim3(256), 0, stream,
                       STARTS, DSTS, F1c, F2c, S2, bias_c, out, N);
}

// Round 6
// 293.218 us; speedup vs baseline: 4.6085x; 1.0474x over previous
//
#include <hip/hip_runtime.h>
#include <hip/hip_bf16.h>
#include <cstddef>
#include <cstdint>

#define IN_DIM 512
#define R_DIM 128
#define F_DIM 64
#define H_NUM 4
#define OUT_DIM 64
#define HF 256  // H_NUM * F_DIM

typedef __attribute__((ext_vector_type(4))) float f32x4;
typedef __attribute__((ext_vector_type(8))) short bf16x8;

typedef const __attribute__((address_space(1))) void gas_void;
typedef __attribute__((address_space(3))) void las_void;

__device__ __forceinline__ float bf2f(ushort u) {
    union { uint i; float f; } v; v.i = ((uint)u) << 16; return v.f;
}
__device__ __forceinline__ ushort f2bf(float f) {
    union { float f; uint i; } v; v.f = f;
    uint r = v.i + 0x7fff + ((v.i >> 16) & 1);
    return (ushort)(r >> 16);
}
__device__ __forceinline__ float u2f(uint u) {
    union { uint i; float f; } v; v.i = u; return v.f;
}

// ---------------------------------------------------------------- zero ints
__global__ __launch_bounds__(256) void zero_i32(int* __restrict__ p, int n) {
    int i = blockIdx.x * 256 + threadIdx.x;
    if (i < n) p[i] = 0;
}

// ------------------------------------------------- fold W_seq @ W_lin (heads)
__global__ __launch_bounds__(256) void wcomb1_kernel(const float* __restrict__ Wlin,
                                                     const float* __restrict__ Wseq,
                                                     ushort* __restrict__ Wc) {
    int idx = blockIdx.x * 256 + threadIdx.x;
    if (idx >= H_NUM * F_DIM * IN_DIM) return;
    int i  = idx & (IN_DIM - 1);
    int hf = idx >> 9;          // h*64 + f
    int h  = hf >> 6;
    const float* ws = Wseq + (size_t)hf * R_DIM;
    const float* wl = Wlin + (size_t)h * R_DIM * IN_DIM + i;
    float acc = 0.0f;
#pragma unroll 8
    for (int r = 0; r < R_DIM; ++r) acc += ws[r] * wl[(size_t)r * IN_DIM];
    Wc[idx] = f2bf(acc);
}

// ---------------------------------------------- fold W_seq_c @ W_lin_c (clf)
__global__ __launch_bounds__(256) void wcomb2_kernel(const float* __restrict__ Wlin,
                                                     const float* __restrict__ Wseq,
                                                     ushort* __restrict__ Wc) {
    int idx = blockIdx.x * 256 + threadIdx.x;
    if (idx >= OUT_DIM * HF) return;
    int j = idx & (HF - 1);
    int o = idx >> 8;
    const float* ws = Wseq + (size_t)o * R_DIM;
    const float* wl = Wlin + j;
    float acc = 0.0f;
#pragma unroll 8
    for (int r = 0; r < R_DIM; ++r) acc += ws[r] * wl[(size_t)r * HF];
    Wc[idx] = f2bf(acc);
}

// ----------------------------- bf16 MFMA GEMM TN, fp32 A converted in-flight
// C[m][n] = sum_k A[m][k]*B[n][k]; fused f1/f2 attention dots in epilogue.
// BM=128, BK=64, 256 threads. HH = BN/64 heads per block (grid.y == 1).
template<int BN, int K, int FS>
__global__ __launch_bounds__(256) void gemm_f32a(const float* __restrict__ A,
                                                 const ushort* __restrict__ B,
                                                 ushort* __restrict__ C,
                                                 int M, int Ntot,
                                                 const float* __restrict__ a1,
                                                 const float* __restrict__ b1,
                                                 const float* __restrict__ a2,
                                                 const float* __restrict__ b2,
                                                 float* __restrict__ f1o,
                                                 float* __restrict__ f2o) {
    constexpr int NF = BN / 16;
    constexpr int HH = BN / 64;
    __shared__ ushort As[128 * 64];
    __shared__ ushort Bs[BN * 64];
    const int tid = threadIdx.x;
    const int wave = tid >> 6;
    const int lane = tid & 63;
    const int lr = lane & 15;
    const int lg = lane >> 4;
    const int m0 = blockIdx.x * 128;
    const int n0 = 0;

    int aoff[2][2], boff[NF][2];
#pragma unroll
    for (int rb = 0; rb < 2; ++rb)
#pragma unroll
        for (int ks = 0; ks < 2; ++ks) {
            int row = wave * 32 + rb * 16 + lr;
            int c = ks * 4 + lg;
            aoff[rb][ks] = row * 128 + ((c ^ (row & 7)) * 16);
        }
#pragma unroll
    for (int cb = 0; cb < NF; ++cb)
#pragma unroll
        for (int ks = 0; ks < 2; ++ks) {
            int row = cb * 16 + lr;
            int c = ks * 4 + lg;
            boff[cb][ks] = row * 128 + ((c ^ (row & 7)) * 16);
        }

    f32x4 acc[2][NF];
#pragma unroll
    for (int rb = 0; rb < 2; ++rb)
#pragma unroll
        for (int cb = 0; cb < NF; ++cb) acc[rb][cb] = (f32x4)0.0f;

    for (int k0 = 0; k0 < K; k0 += 64) {
        // ---- stage B via global_load_lds (pre-swizzled source)
#pragma unroll
        for (int r = 0; r < BN / 32; ++r) {
            int off = r * 4096 + tid * 16;
            int row = off >> 7;
            int kch = ((off >> 4) & 7) ^ (row & 7);
            const ushort* g = B + (size_t)(n0 + row) * K + k0 + kch * 8;
            __builtin_amdgcn_global_load_lds((gas_void*)g,
                                             (las_void*)((char*)Bs + off), 16, 0, 0);
        }
        // ---- stage A: fp32 load -> bf16 cvt -> swizzled ds_write
#pragma unroll
        for (int r = 0; r < 4; ++r) {
            int off = r * 4096 + tid * 16;
            int row = off >> 7;
            int grow = m0 + row;
            if (grow >= M) grow = M - 1;   // clamp (OOB rows never stored)
            int lchunk = (off >> 4) & 7;
            const float* g = A + (size_t)grow * K + k0 + lchunk * 8;
            float4 v0 = *(const float4*)(g);
            float4 v1 = *(const float4*)(g + 4);
            ushort us[8] = {f2bf(v0.x), f2bf(v0.y), f2bf(v0.z), f2bf(v0.w),
                            f2bf(v1.x), f2bf(v1.y), f2bf(v1.z), f2bf(v1.w)};
            int ldsoff = row * 128 + ((lchunk ^ (row & 7)) * 16);
            *(uint4*)((char*)As + ldsoff) = *(const uint4*)us;
        }
        __syncthreads();
#pragma unroll
        for (int ks = 0; ks < 2; ++ks) {
            bf16x8 af[2], bfr[NF];
#pragma unroll
            for (int rb = 0; rb < 2; ++rb)
                af[rb] = *(const bf16x8*)((const char*)As + aoff[rb][ks]);
#pragma unroll
            for (int cb = 0; cb < NF; ++cb)
                bfr[cb] = *(const bf16x8*)((const char*)Bs + boff[cb][ks]);
#pragma unroll
            for (int rb = 0; rb < 2; ++rb)
#pragma unroll
                for (int cb = 0; cb < NF; ++cb)
                    acc[rb][cb] = __builtin_amdgcn_mfma_f32_16x16x32_bf16(
                        af[rb], bfr[cb], acc[rb][cb], 0, 0, 0);
        }
        __syncthreads();
    }

    // ---- epilogue: C store + fused f1/f2 dots
    float a1v[NF], a2v[NF];
#pragma unroll
    for (int cb = 0; cb < NF; ++cb) {
        int col = n0 + cb * 16 + lr;
        a1v[cb] = a1[col];
        a2v[cb] = a2[col];
    }
#pragma unroll
    for (int rb = 0; rb < 2; ++rb) {
        int rowb = m0 + wave * 32 + rb * 16 + lg * 4;
#pragma unroll
        for (int r = 0; r < 4; ++r) {
            int row = rowb + r;
            bool ok = row < M;
#pragma unroll
            for (int hh = 0; hh < HH; ++hh) {
                float p1 = 0.f, p2 = 0.f;
#pragma unroll
                for (int c4 = 0; c4 < 4; ++c4) {
                    int cb = hh * 4 + c4;
                    float v = acc[rb][cb][r];
                    p1 += v * a1v[cb];
                    p2 += v * a2v[cb];
                    if (ok) C[(size_t)row * Ntot + n0 + cb * 16 + lr] = f2bf(v);
                }
#pragma unroll
                for (int m = 1; m < 16; m <<= 1) {
                    p1 += __shfl_xor(p1, m, 64);
                    p2 += __shfl_xor(p2, m, 64);
                }
                if (lr == 0 && ok) {
                    f1o[(size_t)row * FS + hh] = p1 + b1[hh];
                    f2o[(size_t)row * FS + hh] = p2 + b2[hh];
                }
            }
        }
    }
}

// --------------------------- bf16 MFMA GEMM TN with fused f1/f2 epilogue
template<int BN, int K, int FS>
__global__ __launch_bounds__(256) void gemm_bf16(const ushort* __restrict__ A,
                                                 const ushort* __restrict__ B,
                                                 ushort* __restrict__ C,
                                                 int M, int Ntot,
                                                 const float* __restrict__ a1,
                                                 const float* __restrict__ b1,
                                                 const float* __restrict__ a2,
                                                 const float* __restrict__ b2,
                                                 float* __restrict__ f1o,
                                                 float* __restrict__ f2o) {
    constexpr int NF = BN / 16;
    constexpr int HH = BN / 64;
    __shared__ ushort As[128 * 64];
    __shared__ ushort Bs[BN * 64];
    const int tid = threadIdx.x;
    const int wave = tid >> 6;
    const int lane = tid & 63;
    const int lr = lane & 15;
    const int lg = lane >> 4;
    const int m0 = blockIdx.x * 128;
    const int n0 = 0;

    int aoff[2][2], boff[NF][2];
#pragma unroll
    for (int rb = 0; rb < 2; ++rb)
#pragma unroll
        for (int ks = 0; ks < 2; ++ks) {
            int row = wave * 32 + rb * 16 + lr;
            int c = ks * 4 + lg;
            aoff[rb][ks] = row * 128 + ((c ^ (row & 7)) * 16);
        }
#pragma unroll
    for (int cb = 0; cb < NF; ++cb)
#pragma unroll
        for (int ks = 0; ks < 2; ++ks) {
            int row = cb * 16 + lr;
            int c = ks * 4 + lg;
            boff[cb][ks] = row * 128 + ((c ^ (row & 7)) * 16);
        }

    f32x4 acc[2][NF];
#pragma unroll
    for (int rb = 0; rb < 2; ++rb)
#pragma unroll
        for (int cb = 0; cb < NF; ++cb) acc[rb][cb] = (f32x4)0.0f;

    for (int k0 = 0; k0 < K; k0 += 64) {
#pragma unroll
        for (int r = 0; r < 4; ++r) {
            int off = r * 4096 + tid * 16;
            int row = off >> 7;
            int kch = ((off >> 4) & 7) ^ (row & 7);
            const ushort* g = A + (size_t)(m0 + row) * K + k0 + kch * 8;
            __builtin_amdgcn_global_load_lds((gas_void*)g,
                                             (las_void*)((char*)As + off), 16, 0, 0);
        }
#pragma unroll
        for (int r = 0; r < BN / 32; ++r) {
            int off = r * 4096 + tid * 16;
            int row = off >> 7;
            int kch = ((off >> 4) & 7) ^ (row & 7);
            const ushort* g = B + (size_t)(n0 + row) * K + k0 + kch * 8;
            __builtin_amdgcn_global_load_lds((gas_void*)g,
                                             (las_void*)((char*)Bs + off), 16, 0, 0);
        }
        __syncthreads();
#pragma unroll
        for (int ks = 0; ks < 2; ++ks) {
            bf16x8 af[2], bfr[NF];
#pragma unroll
            for (int rb = 0; rb < 2; ++rb)
                af[rb] = *(const bf16x8*)((const char*)As + aoff[rb][ks]);
#pragma unroll
            for (int cb = 0; cb < NF; ++cb)
                bfr[cb] = *(const bf16x8*)((const char*)Bs + boff[cb][ks]);
#pragma unroll
            for (int rb = 0; rb < 2; ++rb)
#pragma unroll
                for (int cb = 0; cb < NF; ++cb)
                    acc[rb][cb] = __builtin_amdgcn_mfma_f32_16x16x32_bf16(
                        af[rb], bfr[cb], acc[rb][cb], 0, 0, 0);
        }
        __syncthreads();
    }

    float a1v[NF], a2v[NF];
#pragma unroll
    for (int cb = 0; cb < NF; ++cb) {
        int col = n0 + cb * 16 + lr;
        a1v[cb] = a1[col];
        a2v[cb] = a2[col];
    }
#pragma unroll
    for (int rb = 0; rb < 2; ++rb) {
        int rowb = m0 + wave * 32 + rb * 16 + lg * 4;
#pragma unroll
        for (int r = 0; r < 4; ++r) {
            int row = rowb + r;
            bool ok = row < M;
#pragma unroll
            for (int hh = 0; hh < HH; ++hh) {
                float p1 = 0.f, p2 = 0.f;
#pragma unroll
                for (int c4 = 0; c4 < 4; ++c4) {
                    int cb = hh * 4 + c4;
                    float v = acc[rb][cb][r];
                    p1 += v * a1v[cb];
                    p2 += v * a2v[cb];
                    if (ok) C[(size_t)row * Ntot + n0 + cb * 16 + lr] = f2bf(v);
                }
#pragma unroll
                for (int m = 1; m < 16; m <<= 1) {
                    p1 += __shfl_xor(p1, m, 64);
                    p2 += __shfl_xor(p2, m, 64);
                }
                if (lr == 0 && ok) {
                    f1o[(size_t)row * FS + hh] = p1 + b1[hh];
                    f2o[(size_t)row * FS + hh] = p2 + b2[hh];
                }
            }
        }
    }
}

// ------------------------------------------------------------ CSR: histogram
__global__ __launch_bounds__(256) void hist_kernel(const int* __restrict__ src,
                                                   int* __restrict__ counts, int E) {
    int e = blockIdx.x * 256 + threadIdx.x;
    if (e < E) atomicAdd(&counts[src[e]], 1);
}

// ----------------------------------------- scan stage 1: per-block excl scan
__global__ __launch_bounds__(256) void scan_blk(const int* __restrict__ counts,
                                                int* __restrict__ lexcl,
                                                int* __restrict__ part, int N) {
    __shared__ int wsum[4];
    int t = threadIdx.x;
    int g = blockIdx.x * 256 + t;
    int lane = t & 63, wid = t >> 6;
    int v = (g < N) ? counts[g] : 0;
    int x = v;
#pragma unroll
    for (int off = 1; off < 64; off <<= 1) {
        int u = __shfl_up(x, off, 64);
        if (lane >= off) x += u;
    }
    if (lane == 63) wsum[wid] = x;
    __syncthreads();
    int woff = 0;
#pragma unroll
    for (int w = 0; w < 3; ++w) if (w < wid) woff += wsum[w];
    int incl = x + woff;
    if (g < N) lexcl[g] = incl - v;
    if (t == 255) part[blockIdx.x] = incl;
}

// --------------------------------- scan stage 2: excl scan of block partials
__global__ __launch_bounds__(256) void scan_part(int* __restrict__ part, int nb) {
    __shared__ int wsum[4];
    int t = threadIdx.x;
    int lane = t & 63, wid = t >> 6;
    int v = (t < nb) ? part[t] : 0;
    int x = v;
#pragma unroll
    for (int off = 1; off < 64; off <<= 1) {
        int u = __shfl_up(x, off, 64);
        if (lane >= off) x += u;
    }
    if (lane == 63) wsum[wid] = x;
    __syncthreads();
    int woff = 0;
#pragma unroll
    for (int w = 0; w < 3; ++w) if (w < wid) woff += wsum[w];
    int incl = x + woff;
    __syncthreads();
    if (t < nb) part[t] = incl - v;
    if (t == 255) part[nb] = incl;   // grand total
}

// ------------------------------------- scan stage 3: add offsets, emit CSR ptrs
__global__ __launch_bounds__(256) void scan_add(const int* __restrict__ lexcl,
                                                const int* __restrict__ part,
                                                int* __restrict__ starts,
                                                int* __restrict__ cursor, int N, int nb) {
    int g = blockIdx.x * 256 + threadIdx.x;
    if (g < N) {
        int s = lexcl[g] + part[blockIdx.x];
        starts[g] = s;
        cursor[g] = s;
    }
    if (g == 0) starts[N] = part[nb];
}

// ------------------------- CSR: position scatter (writes sorted dst directly)
__global__ __launch_bounds__(256) void scatter_kernel(const int* __restrict__ src,
                                                      const int* __restrict__ dst,
                                                      int* __restrict__ cursor,
                                                      int* __restrict__ dsts, int E) {
    int e = blockIdx.x * 256 + threadIdx.x;
    if (e >= E) return;
    int p = atomicAdd(&cursor[src[e]], 1);
    dsts[p] = dst[e];
}

// ----------------------- gather + normalize + bias + ELU, heads (wave/node)
__global__ __launch_bounds__(256) void gather1_kernel(const int* __restrict__ starts,
                                                      const int* __restrict__ dsts,
                                                      const float* __restrict__ f1,
                                                      const float* __restrict__ f2,
                                                      const ushort* __restrict__ S1,
                                                      const float* __restrict__ bias,
                                                      ushort* __restrict__ hcat, int N) {
    int n = (int)((blockIdx.x * blockDim.x + threadIdx.x) >> 6);
    int lane = threadIdx.x & 63;
    if (n >= N) return;
    const int head = lane >> 4;
    const float f1h = f1[(size_t)n * 4 + head];   // uniform per 16-lane group
    int beg = starts[n], end = starts[n + 1];
    float a0 = 0.f, a1 = 0.f, a2 = 0.f, a3 = 0.f, den = 0.f;
    int i = beg;
    for (; i + 4 <= end; i += 4) {
        int4 d4 = *(const int4*)(dsts + i);
        float g0 = f2[(size_t)d4.x * 4 + head];
        float g1 = f2[(size_t)d4.y * 4 + head];
        float g2 = f2[(size_t)d4.z * 4 + head];
        float g3 = f2[(size_t)d4.w * 4 + head];
        uint2 r0 = *(const uint2*)(S1 + (size_t)d4.x * HF + lane * 4);
        uint2 r1 = *(const uint2*)(S1 + (size_t)d4.y * HF + lane * 4);
        uint2 r2 = *(const uint2*)(S1 + (size_t)d4.z * HF + lane * 4);
        uint2 r3 = *(const uint2*)(S1 + (size_t)d4.w * HF + lane * 4);
        float l0 = f1h + g0; l0 = l0 > 0.f ? l0 : 0.2f * l0;
        float l1 = f1h + g1; l1 = l1 > 0.f ? l1 : 0.2f * l1;
        float l2 = f1h + g2; l2 = l2 > 0.f ? l2 : 0.2f * l2;
        float l3 = f1h + g3; l3 = l3 > 0.f ? l3 : 0.2f * l3;
        float c0 = __expf(l0), c1 = __expf(l1), c2 = __expf(l2), c3 = __expf(l3);
        a0 += c0 * u2f(r0.x << 16);        a1 += c0 * u2f(r0.x & 0xffff0000u);
        a2 += c0 * u2f(r0.y << 16);        a3 += c0 * u2f(r0.y & 0xffff0000u);
        a0 += c1 * u2f(r1.x << 16);        a1 += c1 * u2f(r1.x & 0xffff0000u);
        a2 += c1 * u2f(r1.y << 16);        a3 += c1 * u2f(r1.y & 0xffff0000u);
        a0 += c2 * u2f(r2.x << 16);        a1 += c2 * u2f(r2.x & 0xffff0000u);
        a2 += c2 * u2f(r2.y << 16);        a3 += c2 * u2f(r2.y & 0xffff0000u);
        a0 += c3 * u2f(r3.x << 16);        a1 += c3 * u2f(r3.x & 0xffff0000u);
        a2 += c3 * u2f(r3.y << 16);        a3 += c3 * u2f(r3.y & 0xffff0000u);
        den += c0 + c1 + c2 + c3;
    }
    for (; i < end; ++i) {
        int d = dsts[i];
        float g = f2[(size_t)d * 4 + head];
        uint2 r = *(const uint2*)(S1 + (size_t)d * HF + lane * 4);
        float l = f1h + g; l = l > 0.f ? l : 0.2f * l;
        float c = __expf(l);
        a0 += c * u2f(r.x << 16);  a1 += c * u2f(r.x & 0xffff0000u);
        a2 += c * u2f(r.y << 16);  a3 += c * u2f(r.y & 0xffff0000u);
        den += c;
    }
    float rd = __builtin_amdgcn_rcpf(den);
    float4 b = *(const float4*)(bias + lane * 4);
    float v0 = a0 * rd + b.x;
    float v1 = a1 * rd + b.y;
    float v2 = a2 * rd + b.z;
    float v3 = a3 * rd + b.w;
    v0 = v0 > 0.f ? v0 : __expf(v0) - 1.f;
    v1 = v1 > 0.f ? v1 : __expf(v1) - 1.f;
    v2 = v2 > 0.f ? v2 : __expf(v2) - 1.f;
    v3 = v3 > 0.f ? v3 : __expf(v3) - 1.f;
    ushort4 o;
    o.x = f2bf(v0); o.y = f2bf(v1); o.z = f2bf(v2); o.w = f2bf(v3);
    *(ushort4*)(hcat + (size_t)n * HF + lane * 4) = o;
}

// --------------------------- gather + normalize + bias, classifier (wave/node)
__global__ __launch_bounds__(256) void gather2_kernel(const int* __restrict__ starts,
                                                      const int* __restrict__ dsts,
                                                      const float* __restrict__ f1,
                                                      const float* __restrict__ f2,
                                                      const ushort* __restrict__ S2,
                                                      const float* __restrict__ bias,
                                                      float* __restrict__ out, int N) {
    int n = (int)((blockIdx.x * blockDim.x + threadIdx.x) >> 6);
    int lane = threadIdx.x & 63;
    if (n >= N) return;
    const float f1u = f1[n];
    int beg = starts[n], end = starts[n + 1];
    float acc = 0.f, den = 0.f;
    int i = beg;
    for (; i + 4 <= end; i += 4) {
        int4 d4 = *(const int4*)(dsts + i);
        float g0 = f2[d4.x], g1 = f2[d4.y], g2 = f2[d4.z], g3 = f2[d4.w];
        ushort r0 = S2[(size_t)d4.x * OUT_DIM + lane];
        ushort r1 = S2[(size_t)d4.y * OUT_DIM + lane];
        ushort r2 = S2[(size_t)d4.z * OUT_DIM + lane];
        ushort r3 = S2[(size_t)d4.w * OUT_DIM + lane];
        float l0 = f1u + g0; l0 = l0 > 0.f ? l0 : 0.2f * l0;
        float l1 = f1u + g1; l1 = l1 > 0.f ? l1 : 0.2f * l1;
        float l2 = f1u + g2; l2 = l2 > 0.f ? l2 : 0.2f * l2;
        float l3 = f1u + g3; l3 = l3 > 0.f ? l3 : 0.2f * l3;
        float c0 = __expf(l0), c1 = __expf(l1), c2 = __expf(l2), c3 = __expf(l3);
        acc += c0 * bf2f(r0) + c1 * bf2f(r1) + c2 * bf2f(r2) + c3 * bf2f(r3);
        den += c0 + c1 + c2 + c3;
    }
    for (; i < end; ++i) {
        int d = dsts[i];
        float l = f1u + f2[d]; l = l > 0.f ? l : 0.2f * l;
        float c = __expf(l);
        acc += c * bf2f(S2[(size_t)d * OUT_DIM + lane]);
        den += c;
    }
    out[(size_t)n * OUT_DIM + lane] = acc * __builtin_amdgcn_rcpf(den) + bias[lane];
}

// ===========================================================================
extern "C" void kernel_launch(void* const* d_in, const int* in_sizes, int n_in,
                              void* d_out, int out_size, void* d_ws, size_t ws_size,
                              hipStream_t stream) {
    const float* x      = (const float*)d_in[0];
    const int*   edges  = (const int*)d_in[1];
    const float* Wlin_h = (const float*)d_in[2];
    const float* Wseq_h = (const float*)d_in[3];
    const float* a1_h   = (const float*)d_in[4];
    const float* b1_h   = (const float*)d_in[5];
    const float* a2_h   = (const float*)d_in[6];
    const float* b2_h   = (const float*)d_in[7];
    const float* bias_h = (const float*)d_in[8];
    const float* Wlin_c = (const float*)d_in[9];
    const float* Wseq_c = (const float*)d_in[10];
    const float* a1_c   = (const float*)d_in[11];
    const float* b1_c   = (const float*)d_in[12];
    const float* a2_c   = (const float*)d_in[13];
    const float* b2_c   = (const float*)d_in[14];
    const float* bias_c = (const float*)d_in[15];

    const int N = in_sizes[0] / IN_DIM;
    const int E = in_sizes[1] / 2;
    const int* src = edges;
    const int* dst = edges + E;

    char* ws = (char*)d_ws;
    size_t off = 0;
    ushort* WC1   = (ushort*)(ws + off); off += (size_t)HF * IN_DIM * 2;
    ushort* WC2   = (ushort*)(ws + off); off += (size_t)OUT_DIM * HF * 2;
    ushort* S1    = (ushort*)(ws + off); off += (size_t)N * HF * 2;
    ushort* S2    = S1;  // S1 dead after gather1; reuse for S2 [N][64]
    ushort* HCAT  = (ushort*)(ws + off); off += (size_t)N * HF * 2;
    float*  F1    = (float*)(ws + off);  off += (size_t)N * H_NUM * 4;
    float*  F2    = (float*)(ws + off);  off += (size_t)N * H_NUM * 4;
    float*  F1c   = (float*)(ws + off);  off += (size_t)N * 4;
    float*  F2c   = (float*)(ws + off);  off += (size_t)N * 4;
    int* COUNTS   = (int*)(ws + off);    off += (size_t)N * 4;
    int* STARTS   = (int*)(ws + off);    off += ((size_t)N + 1) * 4;
    int* CURSOR   = (int*)(ws + off);    off += (size_t)N * 4;
    int* DSTS     = (int*)(ws + off);    off += (size_t)E * 4;
    int* LEXCL    = (int*)(ws + off);    off += (size_t)N * 4;
    int* PART     = (int*)(ws + off);    off += 512 * 4;

    float* out = (float*)d_out;

    const int eg = (E + 255) / 256;
    const int NB = (N + 255) / 256;

    // ---- CSR build (shared by both layers); DSTS = dst sorted by src
    hipLaunchKernelGGL(zero_i32, dim3(NB), dim3(256), 0, stream, COUNTS, N);
    hipLaunchKernelGGL(hist_kernel, dim3(eg), dim3(256), 0, stream, src, COUNTS, E);
    hipLaunchKernelGGL(scan_blk, dim3(NB), dim3(256), 0, stream, COUNTS, LEXCL, PART, N);
    hipLaunchKernelGGL(scan_part, dim3(1), dim3(256), 0, stream, PART, NB);
    hipLaunchKernelGGL(scan_add, dim3(NB), dim3(256), 0, stream, LEXCL, PART, STARTS, CURSOR, N, NB);
    hipLaunchKernelGGL(scatter_kernel, dim3(eg), dim3(256), 0, stream, src, dst, CURSOR, DSTS, E);

    // ---- fold weights (bf16 out)
    hipLaunchKernelGGL(wcomb1_kernel, dim3((HF * IN_DIM + 255) / 256), dim3(256),
                       0, stream, Wlin_h, Wseq_h, WC1);
    hipLaunchKernelGGL(wcomb2_kernel, dim3((OUT_DIM * HF + 255) / 256), dim3(256),
                       0, stream, Wlin_c, Wseq_c, WC2);

    // ---- layer 1: S1 = x @ Wc1^T  (BN=256 single pass; fused f1/f2 heads)
    hipLaunchKernelGGL((gemm_f32a<HF, IN_DIM, 4>), dim3((N + 127) / 128, 1), dim3(256),
                       0, stream, x, WC1, S1, N, HF,
                       a1_h, b1_h, a2_h, b2_h, F1, F2);

    // ---- gather layer 1 (inline coef + normalize + bias + ELU) -> HCAT bf16
    hipLaunchKernelGGL(gather1_kernel, dim3((N + 3) / 4), dim3(256), 0, stream,
                       STARTS, DSTS, F1, F2, S1, bias_h, HCAT, N);

    // ---- classifier: S2 = hcat @ Wc2^T  (fused f1c/f2c)
    hipLaunchKernelGGL((gemm_bf16<OUT_DIM, HF, 1>), dim3((N + 127) / 128, 1), dim3(256),
                       0, stream, HCAT, WC2, S2, N, OUT_DIM,
                       a1_c, b1_c, a2_c, b2_c, F1c, F2c);

    // ---- gather classifier (inline coef + normalize + bias) -> out fp32
    hipLaunchKernelGGL(gather2_kernel, dim3((N + 3) / 4), dim3(256), 0, stream,
                       STARTS, DSTS, F1c, F2c, S2, bias_c, out, N);
}

// Round 7
// 268.748 us; speedup vs baseline: 5.0281x; 1.0911x over previous
//
#include <hip/hip_runtime.h>
#include <hip/hip_bf16.h>
#include <cstddef>
#include <cstdint>

#define IN_DIM 512
#define R_DIM 128
#define F_DIM 64
#define H_NUM 4
#define OUT_DIM 64
#define HF 256  // H_NUM * F_DIM

typedef __attribute__((ext_vector_type(4))) float f32x4;
typedef __attribute__((ext_vector_type(8))) short bf16x8;

typedef const __attribute__((address_space(1))) void gas_void;
typedef __attribute__((address_space(3))) void las_void;

__device__ __forceinline__ float bf2f(ushort u) {
    union { uint i; float f; } v; v.i = ((uint)u) << 16; return v.f;
}
__device__ __forceinline__ ushort f2bf(float f) {
    union { float f; uint i; } v; v.f = f;
    uint r = v.i + 0x7fff + ((v.i >> 16) & 1);
    return (ushort)(r >> 16);
}
__device__ __forceinline__ float u2f(uint u) {
    union { uint i; float f; } v; v.i = u; return v.f;
}

// ---------------------------------------------------------------- zero ints
__global__ __launch_bounds__(256) void zero_i32(int* __restrict__ p, int n) {
    int i = blockIdx.x * 256 + threadIdx.x;
    if (i < n) p[i] = 0;
}

// ------------------------------------------------- fold W_seq @ W_lin (heads)
__global__ __launch_bounds__(256) void wcomb1_kernel(const float* __restrict__ Wlin,
                                                     const float* __restrict__ Wseq,
                                                     ushort* __restrict__ Wc) {
    int idx = blockIdx.x * 256 + threadIdx.x;
    if (idx >= H_NUM * F_DIM * IN_DIM) return;
    int i  = idx & (IN_DIM - 1);
    int hf = idx >> 9;          // h*64 + f
    int h  = hf >> 6;
    const float* ws = Wseq + (size_t)hf * R_DIM;
    const float* wl = Wlin + (size_t)h * R_DIM * IN_DIM + i;
    float acc = 0.0f;
#pragma unroll 8
    for (int r = 0; r < R_DIM; ++r) acc += ws[r] * wl[(size_t)r * IN_DIM];
    Wc[idx] = f2bf(acc);
}

// ---------------------------------------------- fold W_seq_c @ W_lin_c (clf)
__global__ __launch_bounds__(256) void wcomb2_kernel(const float* __restrict__ Wlin,
                                                     const float* __restrict__ Wseq,
                                                     ushort* __restrict__ Wc) {
    int idx = blockIdx.x * 256 + threadIdx.x;
    if (idx >= OUT_DIM * HF) return;
    int j = idx & (HF - 1);
    int o = idx >> 8;
    const float* ws = Wseq + (size_t)o * R_DIM;
    const float* wl = Wlin + j;
    float acc = 0.0f;
#pragma unroll 8
    for (int r = 0; r < R_DIM; ++r) acc += ws[r] * wl[(size_t)r * HF];
    Wc[idx] = f2bf(acc);
}

// ----------------------------- bf16 MFMA GEMM TN, fp32 A converted in-flight
// BM=64, BK=64, 256 threads (4 waves, one 16-row fragment each).
// Fused f1/f2 attention-dot epilogue. grid.y == 1 (BN = full width).
template<int BN, int K, int FS>
__global__ __launch_bounds__(256) void gemm_f32a(const float* __restrict__ A,
                                                 const ushort* __restrict__ B,
                                                 ushort* __restrict__ C,
                                                 int M, int Ntot,
                                                 const float* __restrict__ a1,
                                                 const float* __restrict__ b1,
                                                 const float* __restrict__ a2,
                                                 const float* __restrict__ b2,
                                                 float* __restrict__ f1o,
                                                 float* __restrict__ f2o) {
    constexpr int NF = BN / 16;
    constexpr int HH = BN / 64;
    __shared__ ushort As[64 * 64];
    __shared__ ushort Bs[BN * 64];
    const int tid = threadIdx.x;
    const int wave = tid >> 6;
    const int lane = tid & 63;
    const int lr = lane & 15;
    const int lg = lane >> 4;
    const int m0 = blockIdx.x * 64;

    // collapsed LDS read bases: row&7 == lr&7 for all fragment rows
    int base[2];
#pragma unroll
    for (int ks = 0; ks < 2; ++ks)
        base[ks] = lr * 128 + (((ks * 4 + lg) ^ (lr & 7)) * 16);
    const int abase0 = wave * 2048 + base[0];
    const int abase1 = wave * 2048 + base[1];

    f32x4 acc[NF];
#pragma unroll
    for (int cb = 0; cb < NF; ++cb) acc[cb] = (f32x4)0.0f;

    for (int k0 = 0; k0 < K; k0 += 64) {
        // ---- stage B via global_load_lds (pre-swizzled source)
#pragma unroll
        for (int r = 0; r < BN / 32; ++r) {
            int off = r * 4096 + tid * 16;
            int row = off >> 7;
            int kch = ((off >> 4) & 7) ^ (row & 7);
            const ushort* g = B + (size_t)row * K + k0 + kch * 8;
            __builtin_amdgcn_global_load_lds((gas_void*)g,
                                             (las_void*)((char*)Bs + off), 16, 0, 0);
        }
        // ---- stage A: fp32 load -> bf16 cvt -> swizzled ds_write (2 rounds)
#pragma unroll
        for (int r = 0; r < 2; ++r) {
            int off = r * 4096 + tid * 16;
            int row = off >> 7;
            int grow = m0 + row;
            if (grow >= M) grow = M - 1;   // clamp (OOB rows never stored)
            int lchunk = (off >> 4) & 7;
            const float* g = A + (size_t)grow * K + k0 + lchunk * 8;
            float4 v0 = *(const float4*)(g);
            float4 v1 = *(const float4*)(g + 4);
            ushort us[8] = {f2bf(v0.x), f2bf(v0.y), f2bf(v0.z), f2bf(v0.w),
                            f2bf(v1.x), f2bf(v1.y), f2bf(v1.z), f2bf(v1.w)};
            int ldsoff = row * 128 + ((lchunk ^ (row & 7)) * 16);
            *(uint4*)((char*)As + ldsoff) = *(const uint4*)us;
        }
        __syncthreads();
        {
            bf16x8 af0 = *(const bf16x8*)((const char*)As + abase0);
            bf16x8 af1 = *(const bf16x8*)((const char*)As + abase1);
#pragma unroll
            for (int cg = 0; cg < NF / 4; ++cg) {
                bf16x8 bfr[4];
#pragma unroll
                for (int j = 0; j < 4; ++j)
                    bfr[j] = *(const bf16x8*)((const char*)Bs + (cg * 4 + j) * 2048 + base[0]);
#pragma unroll
                for (int j = 0; j < 4; ++j)
                    acc[cg * 4 + j] = __builtin_amdgcn_mfma_f32_16x16x32_bf16(
                        af0, bfr[j], acc[cg * 4 + j], 0, 0, 0);
#pragma unroll
                for (int j = 0; j < 4; ++j)
                    bfr[j] = *(const bf16x8*)((const char*)Bs + (cg * 4 + j) * 2048 + base[1]);
#pragma unroll
                for (int j = 0; j < 4; ++j)
                    acc[cg * 4 + j] = __builtin_amdgcn_mfma_f32_16x16x32_bf16(
                        af1, bfr[j], acc[cg * 4 + j], 0, 0, 0);
            }
        }
        __syncthreads();
    }

    // ---- epilogue: C store + fused f1/f2 dots
    float a1v[NF], a2v[NF];
#pragma unroll
    for (int cb = 0; cb < NF; ++cb) {
        int col = cb * 16 + lr;
        a1v[cb] = a1[col];
        a2v[cb] = a2[col];
    }
    const int rowb = m0 + wave * 16 + lg * 4;
#pragma unroll
    for (int r = 0; r < 4; ++r) {
        int row = rowb + r;
        bool ok = row < M;
#pragma unroll
        for (int hh = 0; hh < HH; ++hh) {
            float p1 = 0.f, p2 = 0.f;
#pragma unroll
            for (int c4 = 0; c4 < 4; ++c4) {
                int cb = hh * 4 + c4;
                float v = acc[cb][r];
                p1 += v * a1v[cb];
                p2 += v * a2v[cb];
                if (ok) C[(size_t)row * Ntot + cb * 16 + lr] = f2bf(v);
            }
#pragma unroll
            for (int m = 1; m < 16; m <<= 1) {
                p1 += __shfl_xor(p1, m, 64);
                p2 += __shfl_xor(p2, m, 64);
            }
            if (lr == 0 && ok) {
                f1o[(size_t)row * FS + hh] = p1 + b1[hh];
                f2o[(size_t)row * FS + hh] = p2 + b2[hh];
            }
        }
    }
}

// --------------------------- bf16 MFMA GEMM TN with fused f1/f2 epilogue
// BM=64; A staged via global_load_lds.
template<int BN, int K, int FS>
__global__ __launch_bounds__(256) void gemm_bf16(const ushort* __restrict__ A,
                                                 const ushort* __restrict__ B,
                                                 ushort* __restrict__ C,
                                                 int M, int Ntot,
                                                 const float* __restrict__ a1,
                                                 const float* __restrict__ b1,
                                                 const float* __restrict__ a2,
                                                 const float* __restrict__ b2,
                                                 float* __restrict__ f1o,
                                                 float* __restrict__ f2o) {
    constexpr int NF = BN / 16;
    constexpr int HH = BN / 64;
    __shared__ ushort As[64 * 64];
    __shared__ ushort Bs[BN * 64];
    const int tid = threadIdx.x;
    const int wave = tid >> 6;
    const int lane = tid & 63;
    const int lr = lane & 15;
    const int lg = lane >> 4;
    const int m0 = blockIdx.x * 64;

    int base[2];
#pragma unroll
    for (int ks = 0; ks < 2; ++ks)
        base[ks] = lr * 128 + (((ks * 4 + lg) ^ (lr & 7)) * 16);
    const int abase0 = wave * 2048 + base[0];
    const int abase1 = wave * 2048 + base[1];

    f32x4 acc[NF];
#pragma unroll
    for (int cb = 0; cb < NF; ++cb) acc[cb] = (f32x4)0.0f;

    for (int k0 = 0; k0 < K; k0 += 64) {
#pragma unroll
        for (int r = 0; r < 2; ++r) {
            int off = r * 4096 + tid * 16;
            int row = off >> 7;
            int kch = ((off >> 4) & 7) ^ (row & 7);
            const ushort* g = A + (size_t)(m0 + row) * K + k0 + kch * 8;
            __builtin_amdgcn_global_load_lds((gas_void*)g,
                                             (las_void*)((char*)As + off), 16, 0, 0);
        }
#pragma unroll
        for (int r = 0; r < BN / 32; ++r) {
            int off = r * 4096 + tid * 16;
            int row = off >> 7;
            int kch = ((off >> 4) & 7) ^ (row & 7);
            const ushort* g = B + (size_t)row * K + k0 + kch * 8;
            __builtin_amdgcn_global_load_lds((gas_void*)g,
                                             (las_void*)((char*)Bs + off), 16, 0, 0);
        }
        __syncthreads();
        {
            bf16x8 af0 = *(const bf16x8*)((const char*)As + abase0);
            bf16x8 af1 = *(const bf16x8*)((const char*)As + abase1);
#pragma unroll
            for (int cg = 0; cg < NF / 4; ++cg) {
                bf16x8 bfr[4];
#pragma unroll
                for (int j = 0; j < 4; ++j)
                    bfr[j] = *(const bf16x8*)((const char*)Bs + (cg * 4 + j) * 2048 + base[0]);
#pragma unroll
                for (int j = 0; j < 4; ++j)
                    acc[cg * 4 + j] = __builtin_amdgcn_mfma_f32_16x16x32_bf16(
                        af0, bfr[j], acc[cg * 4 + j], 0, 0, 0);
#pragma unroll
                for (int j = 0; j < 4; ++j)
                    bfr[j] = *(const bf16x8*)((const char*)Bs + (cg * 4 + j) * 2048 + base[1]);
#pragma unroll
                for (int j = 0; j < 4; ++j)
                    acc[cg * 4 + j] = __builtin_amdgcn_mfma_f32_16x16x32_bf16(
                        af1, bfr[j], acc[cg * 4 + j], 0, 0, 0);
            }
        }
        __syncthreads();
    }

    float a1v[NF], a2v[NF];
#pragma unroll
    for (int cb = 0; cb < NF; ++cb) {
        int col = cb * 16 + lr;
        a1v[cb] = a1[col];
        a2v[cb] = a2[col];
    }
    const int rowb = m0 + wave * 16 + lg * 4;
#pragma unroll
    for (int r = 0; r < 4; ++r) {
        int row = rowb + r;
        bool ok = row < M;
#pragma unroll
        for (int hh = 0; hh < HH; ++hh) {
            float p1 = 0.f, p2 = 0.f;
#pragma unroll
            for (int c4 = 0; c4 < 4; ++c4) {
                int cb = hh * 4 + c4;
                float v = acc[cb][r];
                p1 += v * a1v[cb];
                p2 += v * a2v[cb];
                if (ok) C[(size_t)row * Ntot + cb * 16 + lr] = f2bf(v);
            }
#pragma unroll
            for (int m = 1; m < 16; m <<= 1) {
                p1 += __shfl_xor(p1, m, 64);
                p2 += __shfl_xor(p2, m, 64);
            }
            if (lr == 0 && ok) {
                f1o[(size_t)row * FS + hh] = p1 + b1[hh];
                f2o[(size_t)row * FS + hh] = p2 + b2[hh];
            }
        }
    }
}

// ------------------------------------------------------------ CSR: histogram
__global__ __launch_bounds__(256) void hist_kernel(const int* __restrict__ src,
                                                   int* __restrict__ counts, int E) {
    int e = blockIdx.x * 256 + threadIdx.x;
    if (e < E) atomicAdd(&counts[src[e]], 1);
}

// ----------------------------------------- scan stage 1: per-block excl scan
__global__ __launch_bounds__(256) void scan_blk(const int* __restrict__ counts,
                                                int* __restrict__ lexcl,
                                                int* __restrict__ part, int N) {
    __shared__ int wsum[4];
    int t = threadIdx.x;
    int g = blockIdx.x * 256 + t;
    int lane = t & 63, wid = t >> 6;
    int v = (g < N) ? counts[g] : 0;
    int x = v;
#pragma unroll
    for (int off = 1; off < 64; off <<= 1) {
        int u = __shfl_up(x, off, 64);
        if (lane >= off) x += u;
    }
    if (lane == 63) wsum[wid] = x;
    __syncthreads();
    int woff = 0;
#pragma unroll
    for (int w = 0; w < 3; ++w) if (w < wid) woff += wsum[w];
    int incl = x + woff;
    if (g < N) lexcl[g] = incl - v;
    if (t == 255) part[blockIdx.x] = incl;
}

// --------------------------------- scan stage 2: excl scan of block partials
__global__ __launch_bounds__(256) void scan_part(int* __restrict__ part, int nb) {
    __shared__ int wsum[4];
    int t = threadIdx.x;
    int lane = t & 63, wid = t >> 6;
    int v = (t < nb) ? part[t] : 0;
    int x = v;
#pragma unroll
    for (int off = 1; off < 64; off <<= 1) {
        int u = __shfl_up(x, off, 64);
        if (lane >= off) x += u;
    }
    if (lane == 63) wsum[wid] = x;
    __syncthreads();
    int woff = 0;
#pragma unroll
    for (int w = 0; w < 3; ++w) if (w < wid) woff += wsum[w];
    int incl = x + woff;
    __syncthreads();
    if (t < nb) part[t] = incl - v;
    if (t == 255) part[nb] = incl;   // grand total
}

// ------------------------------------- scan stage 3: add offsets, emit CSR ptrs
__global__ __launch_bounds__(256) void scan_add(const int* __restrict__ lexcl,
                                                const int* __restrict__ part,
                                                int* __restrict__ starts,
                                                int* __restrict__ cursor, int N, int nb) {
    int g = blockIdx.x * 256 + threadIdx.x;
    if (g < N) {
        int s = lexcl[g] + part[blockIdx.x];
        starts[g] = s;
        cursor[g] = s;
    }
    if (g == 0) starts[N] = part[nb];
}

// ------------------------- CSR: position scatter (writes sorted dst directly)
__global__ __launch_bounds__(256) void scatter_kernel(const int* __restrict__ src,
                                                      const int* __restrict__ dst,
                                                      int* __restrict__ cursor,
                                                      int* __restrict__ dsts, int E) {
    int e = blockIdx.x * 256 + threadIdx.x;
    if (e >= E) return;
    int p = atomicAdd(&cursor[src[e]], 1);
    dsts[p] = dst[e];
}

// ----------------------- gather + normalize + bias + ELU, heads (wave/node)
__global__ __launch_bounds__(256) void gather1_kernel(const int* __restrict__ starts,
                                                      const int* __restrict__ dsts,
                                                      const float* __restrict__ f1,
                                                      const float* __restrict__ f2,
                                                      const ushort* __restrict__ S1,
                                                      const float* __restrict__ bias,
                                                      ushort* __restrict__ hcat, int N) {
    int n = (int)((blockIdx.x * blockDim.x + threadIdx.x) >> 6);
    int lane = threadIdx.x & 63;
    if (n >= N) return;
    const int head = lane >> 4;
    const float f1h = f1[(size_t)n * 4 + head];   // uniform per 16-lane group
    int beg = starts[n], end = starts[n + 1];
    float a0 = 0.f, a1 = 0.f, a2 = 0.f, a3 = 0.f, den = 0.f;
    int i = beg;
    for (; i + 4 <= end; i += 4) {
        int4 d4 = *(const int4*)(dsts + i);
        float g0 = f2[(size_t)d4.x * 4 + head];
        float g1 = f2[(size_t)d4.y * 4 + head];
        float g2 = f2[(size_t)d4.z * 4 + head];
        float g3 = f2[(size_t)d4.w * 4 + head];
        uint2 r0 = *(const uint2*)(S1 + (size_t)d4.x * HF + lane * 4);
        uint2 r1 = *(const uint2*)(S1 + (size_t)d4.y * HF + lane * 4);
        uint2 r2 = *(const uint2*)(S1 + (size_t)d4.z * HF + lane * 4);
        uint2 r3 = *(const uint2*)(S1 + (size_t)d4.w * HF + lane * 4);
        float l0 = f1h + g0; l0 = l0 > 0.f ? l0 : 0.2f * l0;
        float l1 = f1h + g1; l1 = l1 > 0.f ? l1 : 0.2f * l1;
        float l2 = f1h + g2; l2 = l2 > 0.f ? l2 : 0.2f * l2;
        float l3 = f1h + g3; l3 = l3 > 0.f ? l3 : 0.2f * l3;
        float c0 = __expf(l0), c1 = __expf(l1), c2 = __expf(l2), c3 = __expf(l3);
        a0 += c0 * u2f(r0.x << 16);        a1 += c0 * u2f(r0.x & 0xffff0000u);
        a2 += c0 * u2f(r0.y << 16);        a3 += c0 * u2f(r0.y & 0xffff0000u);
        a0 += c1 * u2f(r1.x << 16);        a1 += c1 * u2f(r1.x & 0xffff0000u);
        a2 += c1 * u2f(r1.y << 16);        a3 += c1 * u2f(r1.y & 0xffff0000u);
        a0 += c2 * u2f(r2.x << 16);        a1 += c2 * u2f(r2.x & 0xffff0000u);
        a2 += c2 * u2f(r2.y << 16);        a3 += c2 * u2f(r2.y & 0xffff0000u);
        a0 += c3 * u2f(r3.x << 16);        a1 += c3 * u2f(r3.x & 0xffff0000u);
        a2 += c3 * u2f(r3.y << 16);        a3 += c3 * u2f(r3.y & 0xffff0000u);
        den += c0 + c1 + c2 + c3;
    }
    for (; i < end; ++i) {
        int d = dsts[i];
        float g = f2[(size_t)d * 4 + head];
        uint2 r = *(const uint2*)(S1 + (size_t)d * HF + lane * 4);
        float l = f1h + g; l = l > 0.f ? l : 0.2f * l;
        float c = __expf(l);
        a0 += c * u2f(r.x << 16);  a1 += c * u2f(r.x & 0xffff0000u);
        a2 += c * u2f(r.y << 16);  a3 += c * u2f(r.y & 0xffff0000u);
        den += c;
    }
    float rd = __builtin_amdgcn_rcpf(den);
    float4 b = *(const float4*)(bias + lane * 4);
    float v0 = a0 * rd + b.x;
    float v1 = a1 * rd + b.y;
    float v2 = a2 * rd + b.z;
    float v3 = a3 * rd + b.w;
    v0 = v0 > 0.f ? v0 : __expf(v0) - 1.f;
    v1 = v1 > 0.f ? v1 : __expf(v1) - 1.f;
    v2 = v2 > 0.f ? v2 : __expf(v2) - 1.f;
    v3 = v3 > 0.f ? v3 : __expf(v3) - 1.f;
    ushort4 o;
    o.x = f2bf(v0); o.y = f2bf(v1); o.z = f2bf(v2); o.w = f2bf(v3);
    *(ushort4*)(hcat + (size_t)n * HF + lane * 4) = o;
}

// --------------------------- gather + normalize + bias, classifier (wave/node)
__global__ __launch_bounds__(256) void gather2_kernel(const int* __restrict__ starts,
                                                      const int* __restrict__ dsts,
                                                      const float* __restrict__ f1,
                                                      const float* __restrict__ f2,
                                                      const ushort* __restrict__ S2,
                                                      const float* __restrict__ bias,
                                                      float* __restrict__ out, int N) {
    int n = (int)((blockIdx.x * blockDim.x + threadIdx.x) >> 6);
    int lane = threadIdx.x & 63;
    if (n >= N) return;
    const float f1u = f1[n];
    int beg = starts[n], end = starts[n + 1];
    float acc = 0.f, den = 0.f;
    int i = beg;
    for (; i + 4 <= end; i += 4) {
        int4 d4 = *(const int4*)(dsts + i);
        float g0 = f2[d4.x], g1 = f2[d4.y], g2 = f2[d4.z], g3 = f2[d4.w];
        ushort r0 = S2[(size_t)d4.x * OUT_DIM + lane];
        ushort r1 = S2[(size_t)d4.y * OUT_DIM + lane];
        ushort r2 = S2[(size_t)d4.z * OUT_DIM + lane];
        ushort r3 = S2[(size_t)d4.w * OUT_DIM + lane];
        float l0 = f1u + g0; l0 = l0 > 0.f ? l0 : 0.2f * l0;
        float l1 = f1u + g1; l1 = l1 > 0.f ? l1 : 0.2f * l1;
        float l2 = f1u + g2; l2 = l2 > 0.f ? l2 : 0.2f * l2;
        float l3 = f1u + g3; l3 = l3 > 0.f ? l3 : 0.2f * l3;
        float c0 = __expf(l0), c1 = __expf(l1), c2 = __expf(l2), c3 = __expf(l3);
        acc += c0 * bf2f(r0) + c1 * bf2f(r1) + c2 * bf2f(r2) + c3 * bf2f(r3);
        den += c0 + c1 + c2 + c3;
    }
    for (; i < end; ++i) {
        int d = dsts[i];
        float l = f1u + f2[d]; l = l > 0.f ? l : 0.2f * l;
        float c = __expf(l);
        acc += c * bf2f(S2[(size_t)d * OUT_DIM + lane]);
        den += c;
    }
    out[(size_t)n * OUT_DIM + lane] = acc * __builtin_amdgcn_rcpf(den) + bias[lane];
}

// ===========================================================================
extern "C" void kernel_launch(void* const* d_in, const int* in_sizes, int n_in,
                              void* d_out, int out_size, void* d_ws, size_t ws_size,
                              hipStream_t stream) {
    const float* x      = (const float*)d_in[0];
    const int*   edges  = (const int*)d_in[1];
    const float* Wlin_h = (const float*)d_in[2];
    const float* Wseq_h = (const float*)d_in[3];
    const float* a1_h   = (const float*)d_in[4];
    const float* b1_h   = (const float*)d_in[5];
    const float* a2_h   = (const float*)d_in[6];
    const float* b2_h   = (const float*)d_in[7];
    const float* bias_h = (const float*)d_in[8];
    const float* Wlin_c = (const float*)d_in[9];
    const float* Wseq_c = (const float*)d_in[10];
    const float* a1_c   = (const float*)d_in[11];
    const float* b1_c   = (const float*)d_in[12];
    const float* a2_c   = (const float*)d_in[13];
    const float* b2_c   = (const float*)d_in[14];
    const float* bias_c = (const float*)d_in[15];

    const int N = in_sizes[0] / IN_DIM;
    const int E = in_sizes[1] / 2;
    const int* src = edges;
    const int* dst = edges + E;

    char* ws = (char*)d_ws;
    size_t off = 0;
    ushort* WC1   = (ushort*)(ws + off); off += (size_t)HF * IN_DIM * 2;
    ushort* WC2   = (ushort*)(ws + off); off += (size_t)OUT_DIM * HF * 2;
    ushort* S1    = (ushort*)(ws + off); off += (size_t)N * HF * 2;
    ushort* S2    = S1;  // S1 dead after gather1; reuse for S2 [N][64]
    ushort* HCAT  = (ushort*)(ws + off); off += (size_t)N * HF * 2;
    float*  F1    = (float*)(ws + off);  off += (size_t)N * H_NUM * 4;
    float*  F2    = (float*)(ws + off);  off += (size_t)N * H_NUM * 4;
    float*  F1c   = (float*)(ws + off);  off += (size_t)N * 4;
    float*  F2c   = (float*)(ws + off);  off += (size_t)N * 4;
    int* COUNTS   = (int*)(ws + off);    off += (size_t)N * 4;
    int* STARTS   = (int*)(ws + off);    off += ((size_t)N + 1) * 4;
    int* CURSOR   = (int*)(ws + off);    off += (size_t)N * 4;
    int* DSTS     = (int*)(ws + off);    off += (size_t)E * 4;
    int* LEXCL    = (int*)(ws + off);    off += (size_t)N * 4;
    int* PART     = (int*)(ws + off);    off += 512 * 4;

    float* out = (float*)d_out;

    const int eg = (E + 255) / 256;
    const int NB = (N + 255) / 256;

    // ---- CSR build (shared by both layers); DSTS = dst sorted by src
    hipLaunchKernelGGL(zero_i32, dim3(NB), dim3(256), 0, stream, COUNTS, N);
    hipLaunchKernelGGL(hist_kernel, dim3(eg), dim3(256), 0, stream, src, COUNTS, E);
    hipLaunchKernelGGL(scan_blk, dim3(NB), dim3(256), 0, stream, COUNTS, LEXCL, PART, N);
    hipLaunchKernelGGL(scan_part, dim3(1), dim3(256), 0, stream, PART, NB);
    hipLaunchKernelGGL(scan_add, dim3(NB), dim3(256), 0, stream, LEXCL, PART, STARTS, CURSOR, N, NB);
    hipLaunchKernelGGL(scatter_kernel, dim3(eg), dim3(256), 0, stream, src, dst, CURSOR, DSTS, E);

    // ---- fold weights (bf16 out)
    hipLaunchKernelGGL(wcomb1_kernel, dim3((HF * IN_DIM + 255) / 256), dim3(256),
                       0, stream, Wlin_h, Wseq_h, WC1);
    hipLaunchKernelGGL(wcomb2_kernel, dim3((OUT_DIM * HF + 255) / 256), dim3(256),
                       0, stream, Wlin_c, Wseq_c, WC2);

    // ---- layer 1: S1 = x @ Wc1^T  (BM=64; fused f1/f2 heads)
    hipLaunchKernelGGL((gemm_f32a<HF, IN_DIM, 4>), dim3((N + 63) / 64, 1), dim3(256),
                       0, stream, x, WC1, S1, N, HF,
                       a1_h, b1_h, a2_h, b2_h, F1, F2);

    // ---- gather layer 1 (inline coef + normalize + bias + ELU) -> HCAT bf16
    hipLaunchKernelGGL(gather1_kernel, dim3((N + 3) / 4), dim3(256), 0, stream,
                       STARTS, DSTS, F1, F2, S1, bias_h, HCAT, N);

    // ---- classifier: S2 = hcat @ Wc2^T  (BM=64; fused f1c/f2c)
    hipLaunchKernelGGL((gemm_bf16<OUT_DIM, HF, 1>), dim3((N + 63) / 64, 1), dim3(256),
                       0, stream, HCAT, WC2, S2, N, OUT_DIM,
                       a1_c, b1_c, a2_c, b2_c, F1c, F2c);

    // ---- gather classifier (inline coef + normalize + bias) -> out fp32
    hipLaunchKernelGGL(gather2_kernel, dim3((N + 3) / 4), dim3(256), 0, stream,
                       STARTS, DSTS, F1c, F2c, S2, bias_c, out, N);
}

// Round 8
// 263.672 us; speedup vs baseline: 5.1249x; 1.0193x over previous
//
#include <hip/hip_runtime.h>
#include <hip/hip_bf16.h>
#include <cstddef>
#include <cstdint>

#define IN_DIM 512
#define R_DIM 128
#define F_DIM 64
#define H_NUM 4
#define OUT_DIM 64
#define HF 256  // H_NUM * F_DIM

typedef __attribute__((ext_vector_type(4))) float f32x4;
typedef __attribute__((ext_vector_type(8))) short bf16x8;

typedef const __attribute__((address_space(1))) void gas_void;
typedef __attribute__((address_space(3))) void las_void;

__device__ __forceinline__ float bf2f(ushort u) {
    union { uint i; float f; } v; v.i = ((uint)u) << 16; return v.f;
}
__device__ __forceinline__ ushort f2bf(float f) {
    union { float f; uint i; } v; v.f = f;
    uint r = v.i + 0x7fff + ((v.i >> 16) & 1);
    return (ushort)(r >> 16);
}
__device__ __forceinline__ float u2f(uint u) {
    union { uint i; float f; } v; v.i = u; return v.f;
}

// ---------------------------------------------------------------- zero ints
__global__ __launch_bounds__(256) void zero_i32(int* __restrict__ p, int n) {
    int i = blockIdx.x * 256 + threadIdx.x;
    if (i < n) p[i] = 0;
}

// ------------------------------------------------- fold W_seq @ W_lin (heads)
__global__ __launch_bounds__(256) void wcomb1_kernel(const float* __restrict__ Wlin,
                                                     const float* __restrict__ Wseq,
                                                     ushort* __restrict__ Wc) {
    int idx = blockIdx.x * 256 + threadIdx.x;
    if (idx >= H_NUM * F_DIM * IN_DIM) return;
    int i  = idx & (IN_DIM - 1);
    int hf = idx >> 9;          // h*64 + f
    int h  = hf >> 6;
    const float* ws = Wseq + (size_t)hf * R_DIM;
    const float* wl = Wlin + (size_t)h * R_DIM * IN_DIM + i;
    float acc = 0.0f;
#pragma unroll 8
    for (int r = 0; r < R_DIM; ++r) acc += ws[r] * wl[(size_t)r * IN_DIM];
    Wc[idx] = f2bf(acc);
}

// ---------------------------------------------- fold W_seq_c @ W_lin_c (clf)
__global__ __launch_bounds__(256) void wcomb2_kernel(const float* __restrict__ Wlin,
                                                     const float* __restrict__ Wseq,
                                                     ushort* __restrict__ Wc) {
    int idx = blockIdx.x * 256 + threadIdx.x;
    if (idx >= OUT_DIM * HF) return;
    int j = idx & (HF - 1);
    int o = idx >> 8;
    const float* ws = Wseq + (size_t)o * R_DIM;
    const float* wl = Wlin + j;
    float acc = 0.0f;
#pragma unroll 8
    for (int r = 0; r < R_DIM; ++r) acc += ws[r] * wl[(size_t)r * HF];
    Wc[idx] = f2bf(acc);
}

// ----------------------------- bf16 MFMA GEMM TN, fp32 A converted in-flight
// BM=64, BK=64, 256 threads (4 waves, one 16-row fragment each).
// Fused f1/f2 attention-dot epilogue. grid.y == 1 (BN = full width).
template<int BN, int K, int FS>
__global__ __launch_bounds__(256) void gemm_f32a(const float* __restrict__ A,
                                                 const ushort* __restrict__ B,
                                                 ushort* __restrict__ C,
                                                 int M, int Ntot,
                                                 const float* __restrict__ a1,
                                                 const float* __restrict__ b1,
                                                 const float* __restrict__ a2,
                                                 const float* __restrict__ b2,
                                                 float* __restrict__ f1o,
                                                 float* __restrict__ f2o) {
    constexpr int NF = BN / 16;
    constexpr int HH = BN / 64;
    __shared__ ushort As[64 * 64];
    __shared__ ushort Bs[BN * 64];
    const int tid = threadIdx.x;
    const int wave = tid >> 6;
    const int lane = tid & 63;
    const int lr = lane & 15;
    const int lg = lane >> 4;
    const int m0 = blockIdx.x * 64;

    int base[2];
#pragma unroll
    for (int ks = 0; ks < 2; ++ks)
        base[ks] = lr * 128 + (((ks * 4 + lg) ^ (lr & 7)) * 16);
    const int abase0 = wave * 2048 + base[0];
    const int abase1 = wave * 2048 + base[1];

    f32x4 acc[NF];
#pragma unroll
    for (int cb = 0; cb < NF; ++cb) acc[cb] = (f32x4)0.0f;

    for (int k0 = 0; k0 < K; k0 += 64) {
        // ---- stage B via global_load_lds (pre-swizzled source)
#pragma unroll
        for (int r = 0; r < BN / 32; ++r) {
            int off = r * 4096 + tid * 16;
            int row = off >> 7;
            int kch = ((off >> 4) & 7) ^ (row & 7);
            const ushort* g = B + (size_t)row * K + k0 + kch * 8;
            __builtin_amdgcn_global_load_lds((gas_void*)g,
                                             (las_void*)((char*)Bs + off), 16, 0, 0);
        }
        // ---- stage A: fp32 load -> bf16 cvt -> swizzled ds_write (2 rounds)
#pragma unroll
        for (int r = 0; r < 2; ++r) {
            int off = r * 4096 + tid * 16;
            int row = off >> 7;
            int grow = m0 + row;
            if (grow >= M) grow = M - 1;   // clamp (OOB rows never stored)
            int lchunk = (off >> 4) & 7;
            const float* g = A + (size_t)grow * K + k0 + lchunk * 8;
            float4 v0 = *(const float4*)(g);
            float4 v1 = *(const float4*)(g + 4);
            ushort us[8] = {f2bf(v0.x), f2bf(v0.y), f2bf(v0.z), f2bf(v0.w),
                            f2bf(v1.x), f2bf(v1.y), f2bf(v1.z), f2bf(v1.w)};
            int ldsoff = row * 128 + ((lchunk ^ (row & 7)) * 16);
            *(uint4*)((char*)As + ldsoff) = *(const uint4*)us;
        }
        __syncthreads();
        {
            bf16x8 af0 = *(const bf16x8*)((const char*)As + abase0);
            bf16x8 af1 = *(const bf16x8*)((const char*)As + abase1);
#pragma unroll
            for (int cg = 0; cg < NF / 4; ++cg) {
                bf16x8 bfr[4];
#pragma unroll
                for (int j = 0; j < 4; ++j)
                    bfr[j] = *(const bf16x8*)((const char*)Bs + (cg * 4 + j) * 2048 + base[0]);
#pragma unroll
                for (int j = 0; j < 4; ++j)
                    acc[cg * 4 + j] = __builtin_amdgcn_mfma_f32_16x16x32_bf16(
                        af0, bfr[j], acc[cg * 4 + j], 0, 0, 0);
#pragma unroll
                for (int j = 0; j < 4; ++j)
                    bfr[j] = *(const bf16x8*)((const char*)Bs + (cg * 4 + j) * 2048 + base[1]);
#pragma unroll
                for (int j = 0; j < 4; ++j)
                    acc[cg * 4 + j] = __builtin_amdgcn_mfma_f32_16x16x32_bf16(
                        af1, bfr[j], acc[cg * 4 + j], 0, 0, 0);
            }
        }
        __syncthreads();
    }

    // ---- epilogue: C store + fused f1/f2 dots
    float a1v[NF], a2v[NF];
#pragma unroll
    for (int cb = 0; cb < NF; ++cb) {
        int col = cb * 16 + lr;
        a1v[cb] = a1[col];
        a2v[cb] = a2[col];
    }
    const int rowb = m0 + wave * 16 + lg * 4;
#pragma unroll
    for (int r = 0; r < 4; ++r) {
        int row = rowb + r;
        bool ok = row < M;
#pragma unroll
        for (int hh = 0; hh < HH; ++hh) {
            float p1 = 0.f, p2 = 0.f;
#pragma unroll
            for (int c4 = 0; c4 < 4; ++c4) {
                int cb = hh * 4 + c4;
                float v = acc[cb][r];
                p1 += v * a1v[cb];
                p2 += v * a2v[cb];
                if (ok) C[(size_t)row * Ntot + cb * 16 + lr] = f2bf(v);
            }
#pragma unroll
            for (int m = 1; m < 16; m <<= 1) {
                p1 += __shfl_xor(p1, m, 64);
                p2 += __shfl_xor(p2, m, 64);
            }
            if (lr == 0 && ok) {
                f1o[(size_t)row * FS + hh] = p1 + b1[hh];
                f2o[(size_t)row * FS + hh] = p2 + b2[hh];
            }
        }
    }
}

// --------------------------- bf16 MFMA GEMM TN with fused f1/f2 epilogue
template<int BN, int K, int FS>
__global__ __launch_bounds__(256) void gemm_bf16(const ushort* __restrict__ A,
                                                 const ushort* __restrict__ B,
                                                 ushort* __restrict__ C,
                                                 int M, int Ntot,
                                                 const float* __restrict__ a1,
                                                 const float* __restrict__ b1,
                                                 const float* __restrict__ a2,
                                                 const float* __restrict__ b2,
                                                 float* __restrict__ f1o,
                                                 float* __restrict__ f2o) {
    constexpr int NF = BN / 16;
    constexpr int HH = BN / 64;
    __shared__ ushort As[64 * 64];
    __shared__ ushort Bs[BN * 64];
    const int tid = threadIdx.x;
    const int wave = tid >> 6;
    const int lane = tid & 63;
    const int lr = lane & 15;
    const int lg = lane >> 4;
    const int m0 = blockIdx.x * 64;

    int base[2];
#pragma unroll
    for (int ks = 0; ks < 2; ++ks)
        base[ks] = lr * 128 + (((ks * 4 + lg) ^ (lr & 7)) * 16);
    const int abase0 = wave * 2048 + base[0];
    const int abase1 = wave * 2048 + base[1];

    f32x4 acc[NF];
#pragma unroll
    for (int cb = 0; cb < NF; ++cb) acc[cb] = (f32x4)0.0f;

    for (int k0 = 0; k0 < K; k0 += 64) {
#pragma unroll
        for (int r = 0; r < 2; ++r) {
            int off = r * 4096 + tid * 16;
            int row = off >> 7;
            int kch = ((off >> 4) & 7) ^ (row & 7);
            const ushort* g = A + (size_t)(m0 + row) * K + k0 + kch * 8;
            __builtin_amdgcn_global_load_lds((gas_void*)g,
                                             (las_void*)((char*)As + off), 16, 0, 0);
        }
#pragma unroll
        for (int r = 0; r < BN / 32; ++r) {
            int off = r * 4096 + tid * 16;
            int row = off >> 7;
            int kch = ((off >> 4) & 7) ^ (row & 7);
            const ushort* g = B + (size_t)row * K + k0 + kch * 8;
            __builtin_amdgcn_global_load_lds((gas_void*)g,
                                             (las_void*)((char*)Bs + off), 16, 0, 0);
        }
        __syncthreads();
        {
            bf16x8 af0 = *(const bf16x8*)((const char*)As + abase0);
            bf16x8 af1 = *(const bf16x8*)((const char*)As + abase1);
#pragma unroll
            for (int cg = 0; cg < NF / 4; ++cg) {
                bf16x8 bfr[4];
#pragma unroll
                for (int j = 0; j < 4; ++j)
                    bfr[j] = *(const bf16x8*)((const char*)Bs + (cg * 4 + j) * 2048 + base[0]);
#pragma unroll
                for (int j = 0; j < 4; ++j)
                    acc[cg * 4 + j] = __builtin_amdgcn_mfma_f32_16x16x32_bf16(
                        af0, bfr[j], acc[cg * 4 + j], 0, 0, 0);
#pragma unroll
                for (int j = 0; j < 4; ++j)
                    bfr[j] = *(const bf16x8*)((const char*)Bs + (cg * 4 + j) * 2048 + base[1]);
#pragma unroll
                for (int j = 0; j < 4; ++j)
                    acc[cg * 4 + j] = __builtin_amdgcn_mfma_f32_16x16x32_bf16(
                        af1, bfr[j], acc[cg * 4 + j], 0, 0, 0);
            }
        }
        __syncthreads();
    }

    float a1v[NF], a2v[NF];
#pragma unroll
    for (int cb = 0; cb < NF; ++cb) {
        int col = cb * 16 + lr;
        a1v[cb] = a1[col];
        a2v[cb] = a2[col];
    }
    const int rowb = m0 + wave * 16 + lg * 4;
#pragma unroll
    for (int r = 0; r < 4; ++r) {
        int row = rowb + r;
        bool ok = row < M;
#pragma unroll
        for (int hh = 0; hh < HH; ++hh) {
            float p1 = 0.f, p2 = 0.f;
#pragma unroll
            for (int c4 = 0; c4 < 4; ++c4) {
                int cb = hh * 4 + c4;
                float v = acc[cb][r];
                p1 += v * a1v[cb];
                p2 += v * a2v[cb];
                if (ok) C[(size_t)row * Ntot + cb * 16 + lr] = f2bf(v);
            }
#pragma unroll
            for (int m = 1; m < 16; m <<= 1) {
                p1 += __shfl_xor(p1, m, 64);
                p2 += __shfl_xor(p2, m, 64);
            }
            if (lr == 0 && ok) {
                f1o[(size_t)row * FS + hh] = p1 + b1[hh];
                f2o[(size_t)row * FS + hh] = p2 + b2[hh];
            }
        }
    }
}

// ------------------------------------------------------------ CSR: histogram
__global__ __launch_bounds__(256) void hist_kernel(const int* __restrict__ src,
                                                   int* __restrict__ counts, int E) {
    int e = blockIdx.x * 256 + threadIdx.x;
    if (e < E) atomicAdd(&counts[src[e]], 1);
}

// ----------------------------------------- scan stage 1: per-block excl scan
__global__ __launch_bounds__(256) void scan_blk(const int* __restrict__ counts,
                                                int* __restrict__ lexcl,
                                                int* __restrict__ part, int N) {
    __shared__ int wsum[4];
    int t = threadIdx.x;
    int g = blockIdx.x * 256 + t;
    int lane = t & 63, wid = t >> 6;
    int v = (g < N) ? counts[g] : 0;
    int x = v;
#pragma unroll
    for (int off = 1; off < 64; off <<= 1) {
        int u = __shfl_up(x, off, 64);
        if (lane >= off) x += u;
    }
    if (lane == 63) wsum[wid] = x;
    __syncthreads();
    int woff = 0;
#pragma unroll
    for (int w = 0; w < 3; ++w) if (w < wid) woff += wsum[w];
    int incl = x + woff;
    if (g < N) lexcl[g] = incl - v;
    if (t == 255) part[blockIdx.x] = incl;
}

// --------------------------------- scan stage 2: excl scan of block partials
__global__ __launch_bounds__(256) void scan_part(int* __restrict__ part, int nb) {
    __shared__ int wsum[4];
    int t = threadIdx.x;
    int lane = t & 63, wid = t >> 6;
    int v = (t < nb) ? part[t] : 0;
    int x = v;
#pragma unroll
    for (int off = 1; off < 64; off <<= 1) {
        int u = __shfl_up(x, off, 64);
        if (lane >= off) x += u;
    }
    if (lane == 63) wsum[wid] = x;
    __syncthreads();
    int woff = 0;
#pragma unroll
    for (int w = 0; w < 3; ++w) if (w < wid) woff += wsum[w];
    int incl = x + woff;
    __syncthreads();
    if (t < nb) part[t] = incl - v;
    if (t == 255) part[nb] = incl;   // grand total
}

// ------------------------------------- scan stage 3: add offsets, emit CSR ptrs
__global__ __launch_bounds__(256) void scan_add(const int* __restrict__ lexcl,
                                                const int* __restrict__ part,
                                                int* __restrict__ starts,
                                                int* __restrict__ cursor, int N, int nb) {
    int g = blockIdx.x * 256 + threadIdx.x;
    if (g < N) {
        int s = lexcl[g] + part[blockIdx.x];
        starts[g] = s;
        cursor[g] = s;
    }
    if (g == 0) starts[N] = part[nb];
}

// ------------------------- CSR: position scatter (writes sorted dst directly)
__global__ __launch_bounds__(256) void scatter_kernel(const int* __restrict__ src,
                                                      const int* __restrict__ dst,
                                                      int* __restrict__ cursor,
                                                      int* __restrict__ dsts, int E) {
    int e = blockIdx.x * 256 + threadIdx.x;
    if (e >= E) return;
    int p = atomicAdd(&cursor[src[e]], 1);
    dsts[p] = dst[e];
}

// ----------------------- gather + normalize + bias + ELU, heads (wave/node)
// lane owns features lane*4..+3 (head = lane>>4); 8-edge unrolled pipeline.
__global__ __launch_bounds__(256) void gather1_kernel(const int* __restrict__ starts,
                                                      const int* __restrict__ dsts,
                                                      const float* __restrict__ f1,
                                                      const float* __restrict__ f2,
                                                      const ushort* __restrict__ S1,
                                                      const float* __restrict__ bias,
                                                      ushort* __restrict__ hcat, int N) {
    int n = (int)((blockIdx.x * blockDim.x + threadIdx.x) >> 6);
    int lane = threadIdx.x & 63;
    if (n >= N) return;
    const int head = lane >> 4;
    const float f1h = f1[(size_t)n * 4 + head];   // uniform per 16-lane group
    int beg = starts[n], end = starts[n + 1];
    float a0 = 0.f, a1 = 0.f, a2 = 0.f, a3 = 0.f, den = 0.f;
    int i = beg;
    for (; i + 8 <= end; i += 8) {
        int d[8];
        {
            int4 da = *(const int4*)(dsts + i);
            int4 db = *(const int4*)(dsts + i + 4);
            d[0] = da.x; d[1] = da.y; d[2] = da.z; d[3] = da.w;
            d[4] = db.x; d[5] = db.y; d[6] = db.z; d[7] = db.w;
        }
        float g[8];
        uint2 r[8];
#pragma unroll
        for (int j = 0; j < 8; ++j) {
            g[j] = f2[(size_t)d[j] * 4 + head];
            r[j] = *(const uint2*)(S1 + (size_t)d[j] * HF + lane * 4);
        }
#pragma unroll
        for (int j = 0; j < 8; ++j) {
            float l = f1h + g[j]; l = l > 0.f ? l : 0.2f * l;
            float c = __expf(l);
            a0 += c * u2f(r[j].x << 16);
            a1 += c * u2f(r[j].x & 0xffff0000u);
            a2 += c * u2f(r[j].y << 16);
            a3 += c * u2f(r[j].y & 0xffff0000u);
            den += c;
        }
    }
    if (i + 4 <= end) {
        int4 da = *(const int4*)(dsts + i);
        int d[4] = {da.x, da.y, da.z, da.w};
        float g[4];
        uint2 r[4];
#pragma unroll
        for (int j = 0; j < 4; ++j) {
            g[j] = f2[(size_t)d[j] * 4 + head];
            r[j] = *(const uint2*)(S1 + (size_t)d[j] * HF + lane * 4);
        }
#pragma unroll
        for (int j = 0; j < 4; ++j) {
            float l = f1h + g[j]; l = l > 0.f ? l : 0.2f * l;
            float c = __expf(l);
            a0 += c * u2f(r[j].x << 16);
            a1 += c * u2f(r[j].x & 0xffff0000u);
            a2 += c * u2f(r[j].y << 16);
            a3 += c * u2f(r[j].y & 0xffff0000u);
            den += c;
        }
        i += 4;
    }
    for (; i < end; ++i) {
        int d = dsts[i];
        float g = f2[(size_t)d * 4 + head];
        uint2 r = *(const uint2*)(S1 + (size_t)d * HF + lane * 4);
        float l = f1h + g; l = l > 0.f ? l : 0.2f * l;
        float c = __expf(l);
        a0 += c * u2f(r.x << 16);  a1 += c * u2f(r.x & 0xffff0000u);
        a2 += c * u2f(r.y << 16);  a3 += c * u2f(r.y & 0xffff0000u);
        den += c;
    }
    float rd = __builtin_amdgcn_rcpf(den);
    float4 b = *(const float4*)(bias + lane * 4);
    float v0 = a0 * rd + b.x;
    float v1 = a1 * rd + b.y;
    float v2 = a2 * rd + b.z;
    float v3 = a3 * rd + b.w;
    v0 = v0 > 0.f ? v0 : __expf(v0) - 1.f;
    v1 = v1 > 0.f ? v1 : __expf(v1) - 1.f;
    v2 = v2 > 0.f ? v2 : __expf(v2) - 1.f;
    v3 = v3 > 0.f ? v3 : __expf(v3) - 1.f;
    ushort4 o;
    o.x = f2bf(v0); o.y = f2bf(v1); o.z = f2bf(v2); o.w = f2bf(v3);
    *(ushort4*)(hcat + (size_t)n * HF + lane * 4) = o;
}

// --------------------------- gather + normalize + bias, classifier (wave/node)
__global__ __launch_bounds__(256) void gather2_kernel(const int* __restrict__ starts,
                                                      const int* __restrict__ dsts,
                                                      const float* __restrict__ f1,
                                                      const float* __restrict__ f2,
                                                      const ushort* __restrict__ S2,
                                                      const float* __restrict__ bias,
                                                      float* __restrict__ out, int N) {
    int n = (int)((blockIdx.x * blockDim.x + threadIdx.x) >> 6);
    int lane = threadIdx.x & 63;
    if (n >= N) return;
    const float f1u = f1[n];
    int beg = starts[n], end = starts[n + 1];
    float acc = 0.f, den = 0.f;
    int i = beg;
    for (; i + 8 <= end; i += 8) {
        int d[8];
        {
            int4 da = *(const int4*)(dsts + i);
            int4 db = *(const int4*)(dsts + i + 4);
            d[0] = da.x; d[1] = da.y; d[2] = da.z; d[3] = da.w;
            d[4] = db.x; d[5] = db.y; d[6] = db.z; d[7] = db.w;
        }
        float g[8];
        ushort r[8];
#pragma unroll
        for (int j = 0; j < 8; ++j) {
            g[j] = f2[d[j]];
            r[j] = S2[(size_t)d[j] * OUT_DIM + lane];
        }
#pragma unroll
        for (int j = 0; j < 8; ++j) {
            float l = f1u + g[j]; l = l > 0.f ? l : 0.2f * l;
            float c = __expf(l);
            acc += c * bf2f(r[j]);
            den += c;
        }
    }
    if (i + 4 <= end) {
        int4 da = *(const int4*)(dsts + i);
        int d[4] = {da.x, da.y, da.z, da.w};
        float g[4];
        ushort r[4];
#pragma unroll
        for (int j = 0; j < 4; ++j) {
            g[j] = f2[d[j]];
            r[j] = S2[(size_t)d[j] * OUT_DIM + lane];
        }
#pragma unroll
        for (int j = 0; j < 4; ++j) {
            float l = f1u + g[j]; l = l > 0.f ? l : 0.2f * l;
            float c = __expf(l);
            acc += c * bf2f(r[j]);
            den += c;
        }
        i += 4;
    }
    for (; i < end; ++i) {
        int d = dsts[i];
        float l = f1u + f2[d]; l = l > 0.f ? l : 0.2f * l;
        float c = __expf(l);
        acc += c * bf2f(S2[(size_t)d * OUT_DIM + lane]);
        den += c;
    }
    out[(size_t)n * OUT_DIM + lane] = acc * __builtin_amdgcn_rcpf(den) + bias[lane];
}

// ===========================================================================
extern "C" void kernel_launch(void* const* d_in, const int* in_sizes, int n_in,
                              void* d_out, int out_size, void* d_ws, size_t ws_size,
                              hipStream_t stream) {
    const float* x      = (const float*)d_in[0];
    const int*   edges  = (const int*)d_in[1];
    const float* Wlin_h = (const float*)d_in[2];
    const float* Wseq_h = (const float*)d_in[3];
    const float* a1_h   = (const float*)d_in[4];
    const float* b1_h   = (const float*)d_in[5];
    const float* a2_h   = (const float*)d_in[6];
    const float* b2_h   = (const float*)d_in[7];
    const float* bias_h = (const float*)d_in[8];
    const float* Wlin_c = (const float*)d_in[9];
    const float* Wseq_c = (const float*)d_in[10];
    const float* a1_c   = (const float*)d_in[11];
    const float* b1_c   = (const float*)d_in[12];
    const float* a2_c   = (const float*)d_in[13];
    const float* b2_c   = (const float*)d_in[14];
    const float* bias_c = (const float*)d_in[15];

    const int N = in_sizes[0] / IN_DIM;
    const int E = in_sizes[1] / 2;
    const int* src = edges;
    const int* dst = edges + E;

    char* ws = (char*)d_ws;
    size_t off = 0;
    ushort* WC1   = (ushort*)(ws + off); off += (size_t)HF * IN_DIM * 2;
    ushort* WC2   = (ushort*)(ws + off); off += (size_t)OUT_DIM * HF * 2;
    ushort* S1    = (ushort*)(ws + off); off += (size_t)N * HF * 2;
    ushort* S2    = S1;  // S1 dead after gather1; reuse for S2 [N][64]
    ushort* HCAT  = (ushort*)(ws + off); off += (size_t)N * HF * 2;
    float*  F1    = (float*)(ws + off);  off += (size_t)N * H_NUM * 4;
    float*  F2    = (float*)(ws + off);  off += (size_t)N * H_NUM * 4;
    float*  F1c   = (float*)(ws + off);  off += (size_t)N * 4;
    float*  F2c   = (float*)(ws + off);  off += (size_t)N * 4;
    int* COUNTS   = (int*)(ws + off);    off += (size_t)N * 4;
    int* STARTS   = (int*)(ws + off);    off += ((size_t)N + 1) * 4;
    int* CURSOR   = (int*)(ws + off);    off += (size_t)N * 4;
    int* DSTS     = (int*)(ws + off);    off += (size_t)E * 4;
    int* LEXCL    = (int*)(ws + off);    off += (size_t)N * 4;
    int* PART     = (int*)(ws + off);    off += 512 * 4;

    float* out = (float*)d_out;

    const int eg = (E + 255) / 256;
    const int NB = (N + 255) / 256;

    // ---- CSR build (shared by both layers); DSTS = dst sorted by src
    hipLaunchKernelGGL(zero_i32, dim3(NB), dim3(256), 0, stream, COUNTS, N);
    hipLaunchKernelGGL(hist_kernel, dim3(eg), dim3(256), 0, stream, src, COUNTS, E);
    hipLaunchKernelGGL(scan_blk, dim3(NB), dim3(256), 0, stream, COUNTS, LEXCL, PART, N);
    hipLaunchKernelGGL(scan_part, dim3(1), dim3(256), 0, stream, PART, NB);
    hipLaunchKernelGGL(scan_add, dim3(NB), dim3(256), 0, stream, LEXCL, PART, STARTS, CURSOR, N, NB);
    hipLaunchKernelGGL(scatter_kernel, dim3(eg), dim3(256), 0, stream, src, dst, CURSOR, DSTS, E);

    // ---- fold weights (bf16 out)
    hipLaunchKernelGGL(wcomb1_kernel, dim3((HF * IN_DIM + 255) / 256), dim3(256),
                       0, stream, Wlin_h, Wseq_h, WC1);
    hipLaunchKernelGGL(wcomb2_kernel, dim3((OUT_DIM * HF + 255) / 256), dim3(256),
                       0, stream, Wlin_c, Wseq_c, WC2);

    // ---- layer 1: S1 = x @ Wc1^T  (BM=64; fused f1/f2 heads)
    hipLaunchKernelGGL((gemm_f32a<HF, IN_DIM, 4>), dim3((N + 63) / 64, 1), dim3(256),
                       0, stream, x, WC1, S1, N, HF,
                       a1_h, b1_h, a2_h, b2_h, F1, F2);

    // ---- gather layer 1 (inline coef + normalize + bias + ELU) -> HCAT bf16
    hipLaunchKernelGGL(gather1_kernel, dim3((N + 3) / 4), dim3(256), 0, stream,
                       STARTS, DSTS, F1, F2, S1, bias_h, HCAT, N);

    // ---- classifier: S2 = hcat @ Wc2^T  (BM=64; fused f1c/f2c)
    hipLaunchKernelGGL((gemm_bf16<OUT_DIM, HF, 1>), dim3((N + 63) / 64, 1), dim3(256),
                       0, stream, HCAT, WC2, S2, N, OUT_DIM,
                       a1_c, b1_c, a2_c, b2_c, F1c, F2c);

    // ---- gather classifier (inline coef + normalize + bias) -> out fp32
    hipLaunchKernelGGL(gather2_kernel, dim3((N + 3) / 4), dim3(256), 0, stream,
                       STARTS, DSTS, F1c, F2c, S2, bias_c, out, N);
}